// Round 1
// baseline (1205.770 us; speedup 1.0000x reference)
//
#include <hip/hip_runtime.h>
#include <math.h>

#define C_S 256
#define NUM_HEADS 8
#define HEAD_DIM 32
#define TOTAL 256
#define S_DIM 256
#define I_DIM 256
#define NROWS (S_DIM * I_DIM)   // 65536
#define LN_EPS 1e-5f

// ---------------------------------------------------------------------------
// Kernel 1: LayerNorm statistics. One wave (64 lanes) per row of 256 channels.
// Writes (mu, rsigma) as float2 per row into the scratch area (front of d_out,
// which is dead until the final GEMM overwrites it).
// ---------------------------------------------------------------------------
__global__ __launch_bounds__(256) void ln_stats_kernel(
    const float* __restrict__ msa, float2* __restrict__ musig) {
  int row  = blockIdx.x * 4 + (threadIdx.x >> 6);
  int lane = threadIdx.x & 63;
  const float4* xr = (const float4*)(msa + (size_t)row * C_S);
  float4 v = xr[lane];                       // 64 lanes x 4 = 256 channels
  float sum = v.x + v.y + v.z + v.w;
  float sq  = v.x*v.x + v.y*v.y + v.z*v.z + v.w*v.w;
  #pragma unroll
  for (int off = 32; off > 0; off >>= 1) {
    sum += __shfl_down(sum, off);
    sq  += __shfl_down(sq, off);
  }
  if (lane == 0) {
    float mu  = sum * (1.0f / 256.0f);
    float var = sq * (1.0f / 256.0f) - mu * mu;
    musig[row] = make_float2(mu, rsqrtf(var + LN_EPS));
  }
}

// ---------------------------------------------------------------------------
// Kernel 2: fused LN-apply + QKVG projection GEMM.
// X_norm(65536 x 256) @ W(256 x 1024), W picked per 64-col tile from Wq/Wk/Wv/Wg.
// Block tile 64x64, 256 threads, thread = 1 row x 16 cols.
// Q/K/V written in (i, h, s, d) layout for the attention kernel;
// G written as sigmoid(xWg + bg) in natural (row, n) layout.
// ---------------------------------------------------------------------------
__global__ __launch_bounds__(256) void proj_kernel(
    const float* __restrict__ msa, const float2* __restrict__ musig,
    const float* __restrict__ gamma, const float* __restrict__ beta,
    const float* __restrict__ Wq, const float* __restrict__ Wk,
    const float* __restrict__ Wv, const float* __restrict__ Wg,
    const float* __restrict__ bg,
    float* __restrict__ Qb, float* __restrict__ Kb,
    float* __restrict__ Vb, float* __restrict__ Gb) {
  __shared__ __align__(16) float Xs[64][68];
  __shared__ __align__(16) float Ws[64][68];

  const int ntile  = blockIdx.x;           // 0..15 over the 1024 output cols
  const int mtile  = blockIdx.y;           // 0..1023 over rows
  const int region = ntile >> 2;           // 0:Q 1:K 2:V 3:G
  const int nloc   = (ntile & 3) * 64;     // col offset inside the 256-wide region
  const float* W   = (region == 0) ? Wq : (region == 1) ? Wk
                    : (region == 2) ? Wv : Wg;
  const int r0  = mtile * 64;
  const int tid = threadIdx.x;
  const int tx  = tid & 3;                 // 4 col-groups of 16
  const int ty  = tid >> 2;                // 64 rows

  float acc[16] = {};

  for (int k0 = 0; k0 < C_S; k0 += 64) {
    #pragma unroll
    for (int it = 0; it < 4; ++it) {
      int idx = tid + it * 256;            // 0..1023 float4 slots
      int row = idx >> 4;                  // 0..63
      int c4  = (idx & 15) << 2;           // 0..60
      float4 xv = *(const float4*)(msa + (size_t)(r0 + row) * C_S + k0 + c4);
      float2 ms = musig[r0 + row];
      float4 gv = *(const float4*)(gamma + k0 + c4);
      float4 bv = *(const float4*)(beta + k0 + c4);
      float4 xn;
      xn.x = (xv.x - ms.x) * ms.y * gv.x + bv.x;
      xn.y = (xv.y - ms.x) * ms.y * gv.y + bv.y;
      xn.z = (xv.z - ms.x) * ms.y * gv.z + bv.z;
      xn.w = (xv.w - ms.x) * ms.y * gv.w + bv.w;
      *(float4*)&Xs[row][c4] = xn;
      *(float4*)&Ws[row][c4] =
          *(const float4*)(W + (size_t)(k0 + row) * TOTAL + nloc + c4);
    }
    __syncthreads();
    #pragma unroll 16
    for (int k = 0; k < 64; ++k) {
      float a = Xs[ty][k];                              // broadcast (4 lanes/addr)
      float4 b0 = *(const float4*)&Ws[k][tx * 16 + 0];  // ds_read_b128
      float4 b1 = *(const float4*)&Ws[k][tx * 16 + 4];
      float4 b2 = *(const float4*)&Ws[k][tx * 16 + 8];
      float4 b3 = *(const float4*)&Ws[k][tx * 16 + 12];
      acc[0]  += a * b0.x; acc[1]  += a * b0.y; acc[2]  += a * b0.z; acc[3]  += a * b0.w;
      acc[4]  += a * b1.x; acc[5]  += a * b1.y; acc[6]  += a * b1.z; acc[7]  += a * b1.w;
      acc[8]  += a * b2.x; acc[9]  += a * b2.y; acc[10] += a * b2.z; acc[11] += a * b2.w;
      acc[12] += a * b3.x; acc[13] += a * b3.y; acc[14] += a * b3.z; acc[15] += a * b3.w;
    }
    __syncthreads();
  }

  // epilogue
  const int r = r0 + ty;
  const int s = r >> 8;        // I_DIM == 256
  const int i = r & 255;
  const int nlbase = nloc + tx * 16;       // 0..255 within the region
  if (region == 3) {
    float* gp = Gb + (size_t)r * TOTAL + nlbase;
    #pragma unroll
    for (int jq = 0; jq < 4; ++jq) {
      float4 o;
      float v0 = acc[jq*4+0] + bg[nlbase + jq*4 + 0];
      float v1 = acc[jq*4+1] + bg[nlbase + jq*4 + 1];
      float v2 = acc[jq*4+2] + bg[nlbase + jq*4 + 2];
      float v3 = acc[jq*4+3] + bg[nlbase + jq*4 + 3];
      o.x = 1.0f / (1.0f + __expf(-v0));
      o.y = 1.0f / (1.0f + __expf(-v1));
      o.z = 1.0f / (1.0f + __expf(-v2));
      o.w = 1.0f / (1.0f + __expf(-v3));
      *(float4*)(gp + jq * 4) = o;
    }
  } else {
    const int h  = nlbase >> 5;
    const int d0 = nlbase & 31;            // 0 or 16
    float* dst = ((region == 0) ? Qb : (region == 1) ? Kb : Vb)
                 + (((size_t)(i * NUM_HEADS + h)) * S_DIM + s) * HEAD_DIM + d0;
    #pragma unroll
    for (int jq = 0; jq < 4; ++jq) {
      *(float4*)(dst + jq * 4) =
          make_float4(acc[jq*4+0], acc[jq*4+1], acc[jq*4+2], acc[jq*4+3]);
    }
  }
}

// ---------------------------------------------------------------------------
// Kernel 3: column attention per (i, h). 2048 blocks, 256 threads = 256 queries.
// K/V staged in LDS (64 KB). Softmax without max-subtraction (scores ~ N(0,1),
// |score| << 80, exp cannot overflow in fp32; identical math to reference).
// Gating fused: reads sigmoid(G) from Gb and overwrites the same addresses
// with the gated output (block-private region -> race-free).
// ---------------------------------------------------------------------------
__global__ __launch_bounds__(256) void attn_kernel(
    const float* __restrict__ Qb, const float* __restrict__ Kb,
    const float* __restrict__ Vb, float* __restrict__ Gb) {
  __shared__ __align__(16) float Ks[S_DIM * HEAD_DIM];   // 32 KB
  __shared__ __align__(16) float Vs[S_DIM * HEAD_DIM];   // 32 KB

  const int ih = blockIdx.x;               // i*8 + h
  const int i  = ih >> 3;
  const int h  = ih & 7;
  const int tid = threadIdx.x;

  const float4* Kp = (const float4*)(Kb + (size_t)ih * S_DIM * HEAD_DIM);
  const float4* Vp = (const float4*)(Vb + (size_t)ih * S_DIM * HEAD_DIM);
  #pragma unroll
  for (int j = 0; j < 8; ++j) {
    int f = tid + j * 256;                 // 0..2047 float4 slots
    ((float4*)Ks)[f] = Kp[f];
    ((float4*)Vs)[f] = Vp[f];
  }
  __syncthreads();

  const int s = tid;
  const float scale = 0.1767766952966369f; // 1/sqrt(32)
  float q[32];
  const float4* Qp = (const float4*)(Qb + ((size_t)ih * S_DIM + s) * HEAD_DIM);
  #pragma unroll
  for (int j = 0; j < 8; ++j) {
    float4 t = Qp[j];
    q[4*j+0] = t.x * scale; q[4*j+1] = t.y * scale;
    q[4*j+2] = t.z * scale; q[4*j+3] = t.w * scale;
  }

  float acc[32] = {};
  float l = 0.0f;
  #pragma unroll 2
  for (int k = 0; k < S_DIM; ++k) {
    const float4* kr = (const float4*)(Ks + k * HEAD_DIM);
    float s0 = 0.f, s1 = 0.f, s2 = 0.f, s3 = 0.f;
    #pragma unroll
    for (int j = 0; j < 8; ++j) {
      float4 t = kr[j];
      s0 += q[4*j+0] * t.x; s1 += q[4*j+1] * t.y;
      s2 += q[4*j+2] * t.z; s3 += q[4*j+3] * t.w;
    }
    float p = __expf((s0 + s1) + (s2 + s3));
    l += p;
    const float4* vr = (const float4*)(Vs + k * HEAD_DIM);
    #pragma unroll
    for (int j = 0; j < 8; ++j) {
      float4 t = vr[j];
      acc[4*j+0] += p * t.x; acc[4*j+1] += p * t.y;
      acc[4*j+2] += p * t.z; acc[4*j+3] += p * t.w;
    }
  }

  const float inv = 1.0f / l;
  float* gp = Gb + ((size_t)(s * I_DIM + i)) * TOTAL + h * HEAD_DIM;
  #pragma unroll
  for (int j = 0; j < 8; ++j) {
    float4 g = *(const float4*)(gp + 4 * j);
    float4 o;
    o.x = g.x * acc[4*j+0] * inv; o.y = g.y * acc[4*j+1] * inv;
    o.z = g.z * acc[4*j+2] * inv; o.w = g.w * acc[4*j+3] * inv;
    *(float4*)(gp + 4 * j) = o;
  }
}

// ---------------------------------------------------------------------------
// Kernel 4: output projection. (65536 x 256) @ Wo(256 x 256) + bo.
// Same tiling as proj_kernel, A = gated vals in natural layout.
// ---------------------------------------------------------------------------
__global__ __launch_bounds__(256) void out_kernel(
    const float* __restrict__ A, const float* __restrict__ Wo,
    const float* __restrict__ bo, float* __restrict__ out) {
  __shared__ __align__(16) float As[64][68];
  __shared__ __align__(16) float Ws[64][68];

  const int ntile = blockIdx.x;            // 0..3
  const int mtile = blockIdx.y;            // 0..1023
  const int nloc  = ntile * 64;
  const int r0  = mtile * 64;
  const int tid = threadIdx.x;
  const int tx  = tid & 3;
  const int ty  = tid >> 2;

  float acc[16] = {};

  for (int k0 = 0; k0 < TOTAL; k0 += 64) {
    #pragma unroll
    for (int it = 0; it < 4; ++it) {
      int idx = tid + it * 256;
      int row = idx >> 4;
      int c4  = (idx & 15) << 2;
      *(float4*)&As[row][c4] =
          *(const float4*)(A + (size_t)(r0 + row) * TOTAL + k0 + c4);
      *(float4*)&Ws[row][c4] =
          *(const float4*)(Wo + (size_t)(k0 + row) * C_S + nloc + c4);
    }
    __syncthreads();
    #pragma unroll 16
    for (int k = 0; k < 64; ++k) {
      float a = As[ty][k];
      float4 b0 = *(const float4*)&Ws[k][tx * 16 + 0];
      float4 b1 = *(const float4*)&Ws[k][tx * 16 + 4];
      float4 b2 = *(const float4*)&Ws[k][tx * 16 + 8];
      float4 b3 = *(const float4*)&Ws[k][tx * 16 + 12];
      acc[0]  += a * b0.x; acc[1]  += a * b0.y; acc[2]  += a * b0.z; acc[3]  += a * b0.w;
      acc[4]  += a * b1.x; acc[5]  += a * b1.y; acc[6]  += a * b1.z; acc[7]  += a * b1.w;
      acc[8]  += a * b2.x; acc[9]  += a * b2.y; acc[10] += a * b2.z; acc[11] += a * b2.w;
      acc[12] += a * b3.x; acc[13] += a * b3.y; acc[14] += a * b3.z; acc[15] += a * b3.w;
    }
    __syncthreads();
  }

  const int r = r0 + ty;
  float* op = out + (size_t)r * C_S + nloc + tx * 16;
  #pragma unroll
  for (int jq = 0; jq < 4; ++jq) {
    int n = nloc + tx * 16 + jq * 4;
    float4 o = make_float4(acc[jq*4+0] + bo[n+0], acc[jq*4+1] + bo[n+1],
                           acc[jq*4+2] + bo[n+2], acc[jq*4+3] + bo[n+3]);
    *(float4*)(op + jq * 4) = o;
  }
}

// ---------------------------------------------------------------------------
extern "C" void kernel_launch(void* const* d_in, const int* in_sizes, int n_in,
                              void* d_out, int out_size, void* d_ws, size_t ws_size,
                              hipStream_t stream) {
  const float* msa   = (const float*)d_in[0];
  const float* gamma = (const float*)d_in[1];
  const float* beta  = (const float*)d_in[2];
  const float* Wq    = (const float*)d_in[3];
  const float* Wk    = (const float*)d_in[4];
  const float* Wv    = (const float*)d_in[5];
  const float* Wg    = (const float*)d_in[6];
  const float* bg    = (const float*)d_in[7];
  const float* Wo    = (const float*)d_in[8];
  const float* bo    = (const float*)d_in[9];
  float* out = (float*)d_out;

  // Workspace: exactly 4 x 64 MiB = 256 MiB.
  const size_t buf = (size_t)NROWS * TOTAL;      // 16.78M floats
  float* Qb = (float*)d_ws;        // (i,h,s,d)
  float* Kb = Qb + buf;            // (i,h,s,d)
  float* Vb = Kb + buf;            // (i,h,s,d)
  float* Gb = Vb + buf;            // (row, n); overwritten in-place with gated vals
  // LN stats (512 KB) live at the front of d_out; dead before out_kernel writes.
  float2* musig = (float2*)d_out;

  ln_stats_kernel<<<NROWS / 4, 256, 0, stream>>>(msa, musig);
  proj_kernel<<<dim3(16, 1024), 256, 0, stream>>>(msa, musig, gamma, beta,
                                                  Wq, Wk, Wv, Wg, bg,
                                                  Qb, Kb, Vb, Gb);
  attn_kernel<<<I_DIM * NUM_HEADS, 256, 0, stream>>>(Qb, Kb, Vb, Gb);
  out_kernel<<<dim3(4, 1024), 256, 0, stream>>>(Gb, Wo, bo, out);
}

// Round 2
// 682.937 us; speedup vs baseline: 1.7656x; 1.7656x over previous
//
#include <hip/hip_runtime.h>
#include <math.h>

#define C_S 256
#define NUM_HEADS 8
#define HEAD_DIM 32
#define TOTAL 256
#define S_DIM 256
#define I_DIM 256
#define NROWS (S_DIM * I_DIM)   // 65536
#define LN_EPS 1e-5f

typedef __attribute__((ext_vector_type(8))) short bf16x8;   // 8 bf16 = 4 VGPR
typedef __attribute__((ext_vector_type(4))) float f32x4;

// fp32 -> bf16 (RNE) and back, as raw int16 bit patterns.
__device__ __forceinline__ short f2bf(float x) {
  unsigned u = __float_as_uint(x);
  u += 0x7FFFu + ((u >> 16) & 1u);
  return (short)(u >> 16);
}
__device__ __forceinline__ float bf2f(short h) {
  return __uint_as_float(((unsigned)(unsigned short)h) << 16);
}

// ---------------------------------------------------------------------------
// Kernel 1: LayerNorm statistics. One wave per row. (mu, rsigma) -> front of
// d_out (dead until out_kernel overwrites it; proj consumes it first).
// ---------------------------------------------------------------------------
__global__ __launch_bounds__(256) void ln_stats_kernel(
    const float* __restrict__ msa, float2* __restrict__ musig) {
  int row  = blockIdx.x * 4 + (threadIdx.x >> 6);
  int lane = threadIdx.x & 63;
  const float4* xr = (const float4*)(msa + (size_t)row * C_S);
  float4 v = xr[lane];
  float sum = v.x + v.y + v.z + v.w;
  float sq  = v.x*v.x + v.y*v.y + v.z*v.z + v.w*v.w;
  #pragma unroll
  for (int off = 32; off > 0; off >>= 1) {
    sum += __shfl_down(sum, off);
    sq  += __shfl_down(sq, off);
  }
  if (lane == 0) {
    float mu  = sum * (1.0f / 256.0f);
    float var = sq * (1.0f / 256.0f) - mu * mu;
    musig[row] = make_float2(mu, rsqrtf(var + LN_EPS));
  }
}

// ---------------------------------------------------------------------------
// Kernel 2: fused LN + QKVG projection, split-bf16 MFMA.
// X(65536x256) @ W(256x1024).  Block tile 128x128, BK=32, 4 waves, wave =
// 4x4 frags of mfma_f32_16x16x32_bf16, 3 MFMAs per frag-pair (hh, hl, lh).
// A is LN-normalized + hi/lo-split during staging; B (weights) is
// transposed + split during staging (W is 256KB, L2-resident).
// Q/K/V stored fp32 (i,h,s,d); G stored fp32 sigmoid (row,col).
// ---------------------------------------------------------------------------
__global__ __launch_bounds__(256) void proj_kernel(
    const float* __restrict__ msa, const float2* __restrict__ musig,
    const float* __restrict__ gamma, const float* __restrict__ beta,
    const float* __restrict__ Wq, const float* __restrict__ Wk,
    const float* __restrict__ Wv, const float* __restrict__ Wg,
    const float* __restrict__ bg,
    float* __restrict__ Qb, float* __restrict__ Kb,
    float* __restrict__ Vb, float* __restrict__ Gb) {
  // rows padded 32 -> 40 bf16 (80 B = 20 banks: worst 2-way conflict = free)
  __shared__ __align__(16) short Ah[128][40];
  __shared__ __align__(16) short Al[128][40];
  __shared__ __align__(16) short Bh[128][40];
  __shared__ __align__(16) short Bl[128][40];

  const int region = blockIdx.x >> 1;            // 0:Q 1:K 2:V 3:G
  const int nbase  = (blockIdx.x & 1) * 128;     // col offset in region
  const float* W = (region == 0) ? Wq : (region == 1) ? Wk
                  : (region == 2) ? Wv : Wg;
  const int r0  = blockIdx.y * 128;
  const int tid = threadIdx.x;
  const int wave = tid >> 6, lane = tid & 63;
  const int wm = wave >> 1, wn = wave & 1;
  const int lr = lane & 15, quad = lane >> 4;

  const int srow  = tid >> 1;                    // 0..127 (A-row / B-col)
  const int shalf = tid & 1;                     // k half (16 each)

  const float2 ms = musig[r0 + srow];
  const float* arow = msa + (size_t)(r0 + srow) * C_S;

  f32x4 acc[4][4] = {};

  for (int k0 = 0; k0 < C_S; k0 += 32) {
    const int kb = k0 + shalf * 16;
    // ---- global loads + transform (registers only) ----
    bf16x8 avh0, avh1, avl0, avl1;
    #pragma unroll
    for (int q = 0; q < 4; ++q) {
      float4 xv = *(const float4*)(arow + kb + q * 4);
      float4 gv = *(const float4*)(gamma + kb + q * 4);
      float4 bv = *(const float4*)(beta + kb + q * 4);
      float xs0 = (xv.x - ms.x) * ms.y * gv.x + bv.x;
      float xs1 = (xv.y - ms.x) * ms.y * gv.y + bv.y;
      float xs2 = (xv.z - ms.x) * ms.y * gv.z + bv.z;
      float xs3 = (xv.w - ms.x) * ms.y * gv.w + bv.w;
      short h0 = f2bf(xs0), h1 = f2bf(xs1), h2 = f2bf(xs2), h3 = f2bf(xs3);
      short l0 = f2bf(xs0 - bf2f(h0)), l1 = f2bf(xs1 - bf2f(h1));
      short l2 = f2bf(xs2 - bf2f(h2)), l3 = f2bf(xs3 - bf2f(h3));
      if (q < 2) {
        avh0[q*4+0]=h0; avh0[q*4+1]=h1; avh0[q*4+2]=h2; avh0[q*4+3]=h3;
        avl0[q*4+0]=l0; avl0[q*4+1]=l1; avl0[q*4+2]=l2; avl0[q*4+3]=l3;
      } else {
        avh1[(q-2)*4+0]=h0; avh1[(q-2)*4+1]=h1; avh1[(q-2)*4+2]=h2; avh1[(q-2)*4+3]=h3;
        avl1[(q-2)*4+0]=l0; avl1[(q-2)*4+1]=l1; avl1[(q-2)*4+2]=l2; avl1[(q-2)*4+3]=l3;
      }
    }
    const float* wp = W + (size_t)kb * TOTAL + nbase + srow;
    bf16x8 bvh0, bvh1, bvl0, bvl1;
    #pragma unroll
    for (int j = 0; j < 8; ++j) {
      float w0 = wp[(size_t)j * TOTAL];
      float w1 = wp[(size_t)(j + 8) * TOTAL];
      short h0 = f2bf(w0), h1 = f2bf(w1);
      bvh0[j] = h0; bvl0[j] = f2bf(w0 - bf2f(h0));
      bvh1[j] = h1; bvl1[j] = f2bf(w1 - bf2f(h1));
    }
    __syncthreads();   // previous compute done reading LDS
    *(bf16x8*)&Ah[srow][shalf * 16 + 0] = avh0;
    *(bf16x8*)&Ah[srow][shalf * 16 + 8] = avh1;
    *(bf16x8*)&Al[srow][shalf * 16 + 0] = avl0;
    *(bf16x8*)&Al[srow][shalf * 16 + 8] = avl1;
    *(bf16x8*)&Bh[srow][shalf * 16 + 0] = bvh0;
    *(bf16x8*)&Bh[srow][shalf * 16 + 8] = bvh1;
    *(bf16x8*)&Bl[srow][shalf * 16 + 0] = bvl0;
    *(bf16x8*)&Bl[srow][shalf * 16 + 8] = bvl1;
    __syncthreads();

    bf16x8 ah[4], al[4], bh[4], bl[4];
    #pragma unroll
    for (int mt = 0; mt < 4; ++mt) {
      ah[mt] = *(const bf16x8*)&Ah[wm * 64 + mt * 16 + lr][quad * 8];
      al[mt] = *(const bf16x8*)&Al[wm * 64 + mt * 16 + lr][quad * 8];
    }
    #pragma unroll
    for (int nt = 0; nt < 4; ++nt) {
      bh[nt] = *(const bf16x8*)&Bh[wn * 64 + nt * 16 + lr][quad * 8];
      bl[nt] = *(const bf16x8*)&Bl[wn * 64 + nt * 16 + lr][quad * 8];
    }
    #pragma unroll
    for (int mt = 0; mt < 4; ++mt)
      #pragma unroll
      for (int nt = 0; nt < 4; ++nt) {
        acc[mt][nt] = __builtin_amdgcn_mfma_f32_16x16x32_bf16(ah[mt], bh[nt], acc[mt][nt], 0, 0, 0);
        acc[mt][nt] = __builtin_amdgcn_mfma_f32_16x16x32_bf16(ah[mt], bl[nt], acc[mt][nt], 0, 0, 0);
        acc[mt][nt] = __builtin_amdgcn_mfma_f32_16x16x32_bf16(al[mt], bh[nt], acc[mt][nt], 0, 0, 0);
      }
  }

  // ---- epilogue ----
  if (region == 3) {
    #pragma unroll
    for (int nt = 0; nt < 4; ++nt) {
      const int col = nbase + wn * 64 + nt * 16 + lr;     // 0..255
      const float b = bg[col];
      #pragma unroll
      for (int mt = 0; mt < 4; ++mt)
        #pragma unroll
        for (int reg = 0; reg < 4; ++reg) {
          const int row = r0 + wm * 64 + mt * 16 + quad * 4 + reg;
          float v = acc[mt][nt][reg] + b;
          Gb[(size_t)row * TOTAL + col] = 1.0f / (1.0f + __expf(-v));
        }
    }
  } else {
    float* dst0 = (region == 0) ? Qb : (region == 1) ? Kb : Vb;
    #pragma unroll
    for (int nt = 0; nt < 4; ++nt) {
      const int col = nbase + wn * 64 + nt * 16 + lr;
      const int h = col >> 5, d = col & 31;
      #pragma unroll
      for (int mt = 0; mt < 4; ++mt)
        #pragma unroll
        for (int reg = 0; reg < 4; ++reg) {
          const int row = r0 + wm * 64 + mt * 16 + quad * 4 + reg;
          const int s = row >> 8, i = row & 255;
          dst0[(((size_t)(i * NUM_HEADS + h)) * S_DIM + s) * HEAD_DIM + d] =
              acc[mt][nt][reg];
        }
    }
  }
}

// ---------------------------------------------------------------------------
// Kernel 3: column attention per (i, h), fp32 VALU (near its 157TF floor).
// Epilogue: gated output split to (hi,lo) bf16 packed into the SAME 4B slots
// of Gb (block-private region -> race-free, zero extra workspace).
// ---------------------------------------------------------------------------
__global__ __launch_bounds__(256) void attn_kernel(
    const float* __restrict__ Qb, const float* __restrict__ Kb,
    const float* __restrict__ Vb, float* __restrict__ Gb) {
  __shared__ __align__(16) float Ks[S_DIM * HEAD_DIM];   // 32 KB
  __shared__ __align__(16) float Vs[S_DIM * HEAD_DIM];   // 32 KB

  const int ih = blockIdx.x;
  const int i  = ih >> 3;
  const int h  = ih & 7;
  const int tid = threadIdx.x;

  const float4* Kp = (const float4*)(Kb + (size_t)ih * S_DIM * HEAD_DIM);
  const float4* Vp = (const float4*)(Vb + (size_t)ih * S_DIM * HEAD_DIM);
  #pragma unroll
  for (int j = 0; j < 8; ++j) {
    int f = tid + j * 256;
    ((float4*)Ks)[f] = Kp[f];
    ((float4*)Vs)[f] = Vp[f];
  }
  __syncthreads();

  const int s = tid;
  const float scale = 0.1767766952966369f; // 1/sqrt(32)
  float q[32];
  const float4* Qp = (const float4*)(Qb + ((size_t)ih * S_DIM + s) * HEAD_DIM);
  #pragma unroll
  for (int j = 0; j < 8; ++j) {
    float4 t = Qp[j];
    q[4*j+0] = t.x * scale; q[4*j+1] = t.y * scale;
    q[4*j+2] = t.z * scale; q[4*j+3] = t.w * scale;
  }

  float acc[32] = {};
  float l = 0.0f;
  #pragma unroll 2
  for (int k = 0; k < S_DIM; ++k) {
    const float4* kr = (const float4*)(Ks + k * HEAD_DIM);
    float s0 = 0.f, s1 = 0.f, s2 = 0.f, s3 = 0.f;
    #pragma unroll
    for (int j = 0; j < 8; ++j) {
      float4 t = kr[j];
      s0 += q[4*j+0] * t.x; s1 += q[4*j+1] * t.y;
      s2 += q[4*j+2] * t.z; s3 += q[4*j+3] * t.w;
    }
    float p = __expf((s0 + s1) + (s2 + s3));
    l += p;
    const float4* vr = (const float4*)(Vs + k * HEAD_DIM);
    #pragma unroll
    for (int j = 0; j < 8; ++j) {
      float4 t = vr[j];
      acc[4*j+0] += p * t.x; acc[4*j+1] += p * t.y;
      acc[4*j+2] += p * t.z; acc[4*j+3] += p * t.w;
    }
  }

  const float inv = 1.0f / l;
  float* gp = Gb + ((size_t)(s * I_DIM + i)) * TOTAL + h * HEAD_DIM;
  #pragma unroll
  for (int j = 0; j < 8; ++j) {
    float4 g = *(const float4*)(gp + 4 * j);
    float o0 = g.x * acc[4*j+0] * inv;
    float o1 = g.y * acc[4*j+1] * inv;
    float o2 = g.z * acc[4*j+2] * inv;
    float o3 = g.w * acc[4*j+3] * inv;
    short h0 = f2bf(o0), h1 = f2bf(o1), h2 = f2bf(o2), h3 = f2bf(o3);
    uint4 pk;
    pk.x = (unsigned short)h0 | ((unsigned)(unsigned short)f2bf(o0 - bf2f(h0)) << 16);
    pk.y = (unsigned short)h1 | ((unsigned)(unsigned short)f2bf(o1 - bf2f(h1)) << 16);
    pk.z = (unsigned short)h2 | ((unsigned)(unsigned short)f2bf(o2 - bf2f(h2)) << 16);
    pk.w = (unsigned short)h3 | ((unsigned)(unsigned short)f2bf(o3 - bf2f(h3)) << 16);
    *(uint4*)(gp + 4 * j) = pk;
  }
}

// ---------------------------------------------------------------------------
// Kernel 4: output projection, split-bf16 MFMA.  A = packed (hi,lo) gated
// vals (unpack in staging); B = Wo split+transposed in staging (L2-resident).
// ---------------------------------------------------------------------------
__global__ __launch_bounds__(256) void out_kernel(
    const unsigned* __restrict__ Ap, const float* __restrict__ Wo,
    const float* __restrict__ bo, float* __restrict__ out) {
  __shared__ __align__(16) short Ah[128][40];
  __shared__ __align__(16) short Al[128][40];
  __shared__ __align__(16) short Bh[128][40];
  __shared__ __align__(16) short Bl[128][40];

  const int n0 = blockIdx.x * 128;
  const int r0 = blockIdx.y * 128;
  const int tid = threadIdx.x;
  const int wave = tid >> 6, lane = tid & 63;
  const int wm = wave >> 1, wn = wave & 1;
  const int lr = lane & 15, quad = lane >> 4;
  const int srow  = tid >> 1;
  const int shalf = tid & 1;

  f32x4 acc[4][4] = {};

  for (int k0 = 0; k0 < TOTAL; k0 += 32) {
    const int kb = k0 + shalf * 16;
    const unsigned* ap = Ap + (size_t)(r0 + srow) * TOTAL + kb;
    bf16x8 avh0, avh1, avl0, avl1;
    #pragma unroll
    for (int j = 0; j < 8; ++j) {
      unsigned w0 = ap[j];
      unsigned w1 = ap[j + 8];
      avh0[j] = (short)(w0 & 0xFFFFu); avl0[j] = (short)(w0 >> 16);
      avh1[j] = (short)(w1 & 0xFFFFu); avl1[j] = (short)(w1 >> 16);
    }
    const float* wp = Wo + (size_t)kb * C_S + n0 + srow;
    bf16x8 bvh0, bvh1, bvl0, bvl1;
    #pragma unroll
    for (int j = 0; j < 8; ++j) {
      float w0 = wp[(size_t)j * C_S];
      float w1 = wp[(size_t)(j + 8) * C_S];
      short h0 = f2bf(w0), h1 = f2bf(w1);
      bvh0[j] = h0; bvl0[j] = f2bf(w0 - bf2f(h0));
      bvh1[j] = h1; bvl1[j] = f2bf(w1 - bf2f(h1));
    }
    __syncthreads();
    *(bf16x8*)&Ah[srow][shalf * 16 + 0] = avh0;
    *(bf16x8*)&Ah[srow][shalf * 16 + 8] = avh1;
    *(bf16x8*)&Al[srow][shalf * 16 + 0] = avl0;
    *(bf16x8*)&Al[srow][shalf * 16 + 8] = avl1;
    *(bf16x8*)&Bh[srow][shalf * 16 + 0] = bvh0;
    *(bf16x8*)&Bh[srow][shalf * 16 + 8] = bvh1;
    *(bf16x8*)&Bl[srow][shalf * 16 + 0] = bvl0;
    *(bf16x8*)&Bl[srow][shalf * 16 + 8] = bvl1;
    __syncthreads();

    bf16x8 ah[4], al[4], bh[4], bl[4];
    #pragma unroll
    for (int mt = 0; mt < 4; ++mt) {
      ah[mt] = *(const bf16x8*)&Ah[wm * 64 + mt * 16 + lr][quad * 8];
      al[mt] = *(const bf16x8*)&Al[wm * 64 + mt * 16 + lr][quad * 8];
    }
    #pragma unroll
    for (int nt = 0; nt < 4; ++nt) {
      bh[nt] = *(const bf16x8*)&Bh[wn * 64 + nt * 16 + lr][quad * 8];
      bl[nt] = *(const bf16x8*)&Bl[wn * 64 + nt * 16 + lr][quad * 8];
    }
    #pragma unroll
    for (int mt = 0; mt < 4; ++mt)
      #pragma unroll
      for (int nt = 0; nt < 4; ++nt) {
        acc[mt][nt] = __builtin_amdgcn_mfma_f32_16x16x32_bf16(ah[mt], bh[nt], acc[mt][nt], 0, 0, 0);
        acc[mt][nt] = __builtin_amdgcn_mfma_f32_16x16x32_bf16(ah[mt], bl[nt], acc[mt][nt], 0, 0, 0);
        acc[mt][nt] = __builtin_amdgcn_mfma_f32_16x16x32_bf16(al[mt], bh[nt], acc[mt][nt], 0, 0, 0);
      }
  }

  #pragma unroll
  for (int nt = 0; nt < 4; ++nt) {
    const int col = n0 + wn * 64 + nt * 16 + lr;
    const float b = bo[col];
    #pragma unroll
    for (int mt = 0; mt < 4; ++mt)
      #pragma unroll
      for (int reg = 0; reg < 4; ++reg) {
        const int row = r0 + wm * 64 + mt * 16 + quad * 4 + reg;
        out[(size_t)row * C_S + col] = acc[mt][nt][reg] + b;
      }
  }
}

// ---------------------------------------------------------------------------
extern "C" void kernel_launch(void* const* d_in, const int* in_sizes, int n_in,
                              void* d_out, int out_size, void* d_ws, size_t ws_size,
                              hipStream_t stream) {
  const float* msa   = (const float*)d_in[0];
  const float* gamma = (const float*)d_in[1];
  const float* beta  = (const float*)d_in[2];
  const float* Wq    = (const float*)d_in[3];
  const float* Wk    = (const float*)d_in[4];
  const float* Wv    = (const float*)d_in[5];
  const float* Wg    = (const float*)d_in[6];
  const float* bg    = (const float*)d_in[7];
  const float* Wo    = (const float*)d_in[8];
  const float* bo    = (const float*)d_in[9];
  float* out = (float*)d_out;

  // Workspace: exactly 4 x 64 MiB = 256 MiB.
  const size_t buf = (size_t)NROWS * TOTAL;
  float* Qb = (float*)d_ws;        // (i,h,s,d) fp32
  float* Kb = Qb + buf;            // (i,h,s,d) fp32
  float* Vb = Kb + buf;            // (i,h,s,d) fp32
  float* Gb = Vb + buf;            // (row,col) fp32 sigmoid, then packed bf16 hi|lo
  // LN stats (512 KB) at front of d_out; consumed by proj, dead before out_kernel.
  float2* musig = (float2*)d_out;

  ln_stats_kernel<<<NROWS / 4, 256, 0, stream>>>(msa, musig);
  proj_kernel<<<dim3(8, 512), 256, 0, stream>>>(msa, musig, gamma, beta,
                                                Wq, Wk, Wv, Wg, bg,
                                                Qb, Kb, Vb, Gb);
  attn_kernel<<<I_DIM * NUM_HEADS, 256, 0, stream>>>(Qb, Kb, Vb, Gb);
  out_kernel<<<dim3(2, 512), 256, 0, stream>>>((const unsigned*)Gb, Wo, bo, out);
}

// Round 3
// 521.258 us; speedup vs baseline: 2.3132x; 1.3102x over previous
//
#include <hip/hip_runtime.h>
#include <math.h>

#define C_S 256
#define NUM_HEADS 8
#define HEAD_DIM 32
#define TOTAL 256
#define S_DIM 256
#define I_DIM 256
#define NROWS (S_DIM * I_DIM)   // 65536
#define LN_EPS 1e-5f

typedef __attribute__((ext_vector_type(8))) short bf16x8;   // 8 bf16 = 4 VGPR
typedef __attribute__((ext_vector_type(4))) float f32x4;

// fp32 -> bf16 (RNE) and back, as raw int16 bit patterns.
__device__ __forceinline__ short f2bf(float x) {
  unsigned u = __float_as_uint(x);
  u += 0x7FFFu + ((u >> 16) & 1u);
  return (short)(u >> 16);
}
__device__ __forceinline__ float bf2f(short h) {
  return __uint_as_float(((unsigned)(unsigned short)h) << 16);
}

// ---------------------------------------------------------------------------
// Kernel 1: LayerNorm statistics. One wave per row. (mu, rsigma) -> front of
// d_out (dead until out_kernel overwrites it; proj consumes it first).
// ---------------------------------------------------------------------------
__global__ __launch_bounds__(256) void ln_stats_kernel(
    const float* __restrict__ msa, float2* __restrict__ musig) {
  int row  = blockIdx.x * 4 + (threadIdx.x >> 6);
  int lane = threadIdx.x & 63;
  const float4* xr = (const float4*)(msa + (size_t)row * C_S);
  float4 v = xr[lane];
  float sum = v.x + v.y + v.z + v.w;
  float sq  = v.x*v.x + v.y*v.y + v.z*v.z + v.w*v.w;
  #pragma unroll
  for (int off = 32; off > 0; off >>= 1) {
    sum += __shfl_down(sum, off);
    sq  += __shfl_down(sq, off);
  }
  if (lane == 0) {
    float mu  = sum * (1.0f / 256.0f);
    float var = sq * (1.0f / 256.0f) - mu * mu;
    musig[row] = make_float2(mu, rsqrtf(var + LN_EPS));
  }
}

// ---------------------------------------------------------------------------
// Kernel 2: fused LN + QKVG projection, split-bf16 MFMA (mainloop = R2).
// Epilogue: Q (pre-scaled by log2e/sqrt(32)) and K written as bf16 hi/lo
// planes in (i,h,s,d); V fp32 (i,h,s,d); G fp32 sigmoid (row,col).
// ---------------------------------------------------------------------------
__global__ __launch_bounds__(256) void proj_kernel(
    const float* __restrict__ msa, const float2* __restrict__ musig,
    const float* __restrict__ gamma, const float* __restrict__ beta,
    const float* __restrict__ Wq, const float* __restrict__ Wk,
    const float* __restrict__ Wv, const float* __restrict__ Wg,
    const float* __restrict__ bg,
    ushort* __restrict__ Qhi, ushort* __restrict__ Qlo,
    ushort* __restrict__ Khi, ushort* __restrict__ Klo,
    float* __restrict__ Vb, float* __restrict__ Gb) {
  __shared__ __align__(16) short Ah[128][40];
  __shared__ __align__(16) short Al[128][40];
  __shared__ __align__(16) short Bh[128][40];
  __shared__ __align__(16) short Bl[128][40];

  const int region = blockIdx.x >> 1;            // 0:Q 1:K 2:V 3:G
  const int nbase  = (blockIdx.x & 1) * 128;
  const float* W = (region == 0) ? Wq : (region == 1) ? Wk
                  : (region == 2) ? Wv : Wg;
  const int r0  = blockIdx.y * 128;
  const int tid = threadIdx.x;
  const int wave = tid >> 6, lane = tid & 63;
  const int wm = wave >> 1, wn = wave & 1;
  const int lr = lane & 15, quad = lane >> 4;

  const int srow  = tid >> 1;
  const int shalf = tid & 1;

  const float2 ms = musig[r0 + srow];
  const float* arow = msa + (size_t)(r0 + srow) * C_S;

  f32x4 acc[4][4] = {};

  for (int k0 = 0; k0 < C_S; k0 += 32) {
    const int kb = k0 + shalf * 16;
    bf16x8 avh0, avh1, avl0, avl1;
    #pragma unroll
    for (int q = 0; q < 4; ++q) {
      float4 xv = *(const float4*)(arow + kb + q * 4);
      float4 gv = *(const float4*)(gamma + kb + q * 4);
      float4 bv = *(const float4*)(beta + kb + q * 4);
      float xs0 = (xv.x - ms.x) * ms.y * gv.x + bv.x;
      float xs1 = (xv.y - ms.x) * ms.y * gv.y + bv.y;
      float xs2 = (xv.z - ms.x) * ms.y * gv.z + bv.z;
      float xs3 = (xv.w - ms.x) * ms.y * gv.w + bv.w;
      short h0 = f2bf(xs0), h1 = f2bf(xs1), h2 = f2bf(xs2), h3 = f2bf(xs3);
      short l0 = f2bf(xs0 - bf2f(h0)), l1 = f2bf(xs1 - bf2f(h1));
      short l2 = f2bf(xs2 - bf2f(h2)), l3 = f2bf(xs3 - bf2f(h3));
      if (q < 2) {
        avh0[q*4+0]=h0; avh0[q*4+1]=h1; avh0[q*4+2]=h2; avh0[q*4+3]=h3;
        avl0[q*4+0]=l0; avl0[q*4+1]=l1; avl0[q*4+2]=l2; avl0[q*4+3]=l3;
      } else {
        avh1[(q-2)*4+0]=h0; avh1[(q-2)*4+1]=h1; avh1[(q-2)*4+2]=h2; avh1[(q-2)*4+3]=h3;
        avl1[(q-2)*4+0]=l0; avl1[(q-2)*4+1]=l1; avl1[(q-2)*4+2]=l2; avl1[(q-2)*4+3]=l3;
      }
    }
    const float* wp = W + (size_t)kb * TOTAL + nbase + srow;
    bf16x8 bvh0, bvh1, bvl0, bvl1;
    #pragma unroll
    for (int j = 0; j < 8; ++j) {
      float w0 = wp[(size_t)j * TOTAL];
      float w1 = wp[(size_t)(j + 8) * TOTAL];
      short h0 = f2bf(w0), h1 = f2bf(w1);
      bvh0[j] = h0; bvl0[j] = f2bf(w0 - bf2f(h0));
      bvh1[j] = h1; bvl1[j] = f2bf(w1 - bf2f(h1));
    }
    __syncthreads();
    *(bf16x8*)&Ah[srow][shalf * 16 + 0] = avh0;
    *(bf16x8*)&Ah[srow][shalf * 16 + 8] = avh1;
    *(bf16x8*)&Al[srow][shalf * 16 + 0] = avl0;
    *(bf16x8*)&Al[srow][shalf * 16 + 8] = avl1;
    *(bf16x8*)&Bh[srow][shalf * 16 + 0] = bvh0;
    *(bf16x8*)&Bh[srow][shalf * 16 + 8] = bvh1;
    *(bf16x8*)&Bl[srow][shalf * 16 + 0] = bvl0;
    *(bf16x8*)&Bl[srow][shalf * 16 + 8] = bvl1;
    __syncthreads();

    bf16x8 ah[4], al[4], bh[4], bl[4];
    #pragma unroll
    for (int mt = 0; mt < 4; ++mt) {
      ah[mt] = *(const bf16x8*)&Ah[wm * 64 + mt * 16 + lr][quad * 8];
      al[mt] = *(const bf16x8*)&Al[wm * 64 + mt * 16 + lr][quad * 8];
    }
    #pragma unroll
    for (int nt = 0; nt < 4; ++nt) {
      bh[nt] = *(const bf16x8*)&Bh[wn * 64 + nt * 16 + lr][quad * 8];
      bl[nt] = *(const bf16x8*)&Bl[wn * 64 + nt * 16 + lr][quad * 8];
    }
    #pragma unroll
    for (int mt = 0; mt < 4; ++mt)
      #pragma unroll
      for (int nt = 0; nt < 4; ++nt) {
        acc[mt][nt] = __builtin_amdgcn_mfma_f32_16x16x32_bf16(ah[mt], bh[nt], acc[mt][nt], 0, 0, 0);
        acc[mt][nt] = __builtin_amdgcn_mfma_f32_16x16x32_bf16(ah[mt], bl[nt], acc[mt][nt], 0, 0, 0);
        acc[mt][nt] = __builtin_amdgcn_mfma_f32_16x16x32_bf16(al[mt], bh[nt], acc[mt][nt], 0, 0, 0);
      }
  }

  // ---- epilogue ----
  if (region == 3) {
    #pragma unroll
    for (int nt = 0; nt < 4; ++nt) {
      const int col = nbase + wn * 64 + nt * 16 + lr;
      const float b = bg[col];
      #pragma unroll
      for (int mt = 0; mt < 4; ++mt)
        #pragma unroll
        for (int reg = 0; reg < 4; ++reg) {
          const int row = r0 + wm * 64 + mt * 16 + quad * 4 + reg;
          float v = acc[mt][nt][reg] + b;
          Gb[(size_t)row * TOTAL + col] = 1.0f / (1.0f + __expf(-v));
        }
    }
  } else if (region == 2) {
    #pragma unroll
    for (int nt = 0; nt < 4; ++nt) {
      const int col = nbase + wn * 64 + nt * 16 + lr;
      const int h = col >> 5, d = col & 31;
      #pragma unroll
      for (int mt = 0; mt < 4; ++mt)
        #pragma unroll
        for (int reg = 0; reg < 4; ++reg) {
          const int row = r0 + wm * 64 + mt * 16 + quad * 4 + reg;
          const int s = row >> 8, i = row & 255;
          Vb[(((size_t)(i * NUM_HEADS + h)) * S_DIM + s) * HEAD_DIM + d] =
              acc[mt][nt][reg];
        }
    }
  } else {
    // Q/K: bf16 hi/lo planes, (i,h,s,d). Q pre-scaled by log2(e)/sqrt(32)
    // so attention softmax is a raw exp2.
    ushort* Phi = (region == 0) ? Qhi : Khi;
    ushort* Plo = (region == 0) ? Qlo : Klo;
    const float scale = (region == 0) ? 0.25503534f : 1.0f;
    #pragma unroll
    for (int nt = 0; nt < 4; ++nt) {
      const int col = nbase + wn * 64 + nt * 16 + lr;
      const int h = col >> 5, d = col & 31;
      #pragma unroll
      for (int mt = 0; mt < 4; ++mt)
        #pragma unroll
        for (int reg = 0; reg < 4; ++reg) {
          const int row = r0 + wm * 64 + mt * 16 + quad * 4 + reg;
          const int s = row >> 8, i = row & 255;
          float v = acc[mt][nt][reg] * scale;
          short hb = f2bf(v);
          size_t off = (((size_t)(i * NUM_HEADS + h)) * S_DIM + s) * HEAD_DIM + d;
          Phi[off] = (ushort)hb;
          Plo[off] = (ushort)f2bf(v - bf2f(hb));
        }
    }
  }
}

// ---------------------------------------------------------------------------
// Kernel 3: MFMA column attention per (i,h). 4 waves x 64 queries.
// scores^T = K.Q^T (split-bf16, K=D=32 in one k-step), exp2 (scale folded
// into Q), P -> bf16 in LDS (wave-private rows, no barrier in the K-loop),
// out^T = Vt.P^T (split V). No max-subtraction and no flash rescaling.
// l accumulated from the ROUNDED P so normalization matches the P used.
// Epilogue: gated output packed (hi|lo) bf16 in place over Gb.
// ---------------------------------------------------------------------------
__global__ __launch_bounds__(256, 2) void attn_kernel(
    const ushort* __restrict__ Qhi, const ushort* __restrict__ Qlo,
    const ushort* __restrict__ Khi, const ushort* __restrict__ Klo,
    const float* __restrict__ Vb, float* __restrict__ Gb) {
  __shared__ __align__(16) ushort Ph[256][72];    // P chunk [s][t-in-chunk]
  __shared__ __align__(16) ushort Vth[32][264];   // V^T hi [d][t]
  __shared__ __align__(16) ushort Vtl[32][264];   // V^T lo [d][t]

  const int ih = blockIdx.x;
  const int i = ih >> 3, h = ih & 7;
  const int tid = threadIdx.x;
  const int wave = tid >> 6, lane = tid & 63;
  const int lr = lane & 15, quad = lane >> 4;
  const int s_base = wave * 64;
  const size_t hbase = (size_t)ih * (S_DIM * HEAD_DIM);

  // ---- stage V -> LDS, transposed + hi/lo split (once per block) ----
  {
    const float4* vp = (const float4*)(Vb + hbase + (size_t)tid * HEAD_DIM);
    #pragma unroll
    for (int j = 0; j < 8; ++j) {
      float4 v = vp[j];
      float vv[4] = {v.x, v.y, v.z, v.w};
      #pragma unroll
      for (int e = 0; e < 4; ++e) {
        short hh = f2bf(vv[e]);
        Vth[j * 4 + e][tid] = (ushort)hh;
        Vtl[j * 4 + e][tid] = (ushort)f2bf(vv[e] - bf2f(hh));
      }
    }
  }
  __syncthreads();   // the only barrier: V is shared across waves

  // ---- persistent Q fragments (B-operand): B[n=s][k=d] ----
  bf16x8 qh[4], ql[4];
  #pragma unroll
  for (int ns = 0; ns < 4; ++ns) {
    size_t off = hbase + (size_t)(s_base + ns * 16 + lr) * HEAD_DIM + quad * 8;
    qh[ns] = *(const bf16x8*)(Qhi + off);
    ql[ns] = *(const bf16x8*)(Qlo + off);
  }

  f32x4 oacc[2][4] = {};
  float lpart[4] = {};

  #pragma unroll 1
  for (int c = 0; c < 4; ++c) {
    const int t0 = c * 64;
    // K fragments (A-operand): A[m=t][k=d]
    bf16x8 kh[4], kl[4];
    #pragma unroll
    for (int mt = 0; mt < 4; ++mt) {
      size_t off = hbase + (size_t)(t0 + mt * 16 + lr) * HEAD_DIM + quad * 8;
      kh[mt] = *(const bf16x8*)(Khi + off);
      kl[mt] = *(const bf16x8*)(Klo + off);
    }
    // scores^T tiles: D[t][s]; lane holds 4 consecutive t at one s
    #pragma unroll
    for (int mt = 0; mt < 4; ++mt) {
      #pragma unroll
      for (int ns = 0; ns < 4; ++ns) {
        f32x4 sc = {};
        sc = __builtin_amdgcn_mfma_f32_16x16x32_bf16(kh[mt], qh[ns], sc, 0, 0, 0);
        sc = __builtin_amdgcn_mfma_f32_16x16x32_bf16(kh[mt], ql[ns], sc, 0, 0, 0);
        sc = __builtin_amdgcn_mfma_f32_16x16x32_bf16(kl[mt], qh[ns], sc, 0, 0, 0);
        ushort4 pk;
        float p0 = exp2f(sc[0]), p1 = exp2f(sc[1]);
        float p2 = exp2f(sc[2]), p3 = exp2f(sc[3]);
        short b0 = f2bf(p0), b1 = f2bf(p1), b2 = f2bf(p2), b3 = f2bf(p3);
        pk.x = (ushort)b0; pk.y = (ushort)b1; pk.z = (ushort)b2; pk.w = (ushort)b3;
        lpart[ns] += (bf2f(b0) + bf2f(b1)) + (bf2f(b2) + bf2f(b3));
        const int srow = s_base + ns * 16 + lr;
        *(ushort4*)&Ph[srow][mt * 16 + quad * 4] = pk;   // ds_write_b64
      }
    }
    // PV: out^T[d][s] += Vt(chunk) x P^T  (A = Vt, B = P)
    #pragma unroll
    for (int ks = 0; ks < 2; ++ks) {
      const int tq = t0 + ks * 32 + quad * 8;
      bf16x8 vh0 = *(const bf16x8*)&Vth[lr][tq];
      bf16x8 vl0 = *(const bf16x8*)&Vtl[lr][tq];
      bf16x8 vh1 = *(const bf16x8*)&Vth[16 + lr][tq];
      bf16x8 vl1 = *(const bf16x8*)&Vtl[16 + lr][tq];
      #pragma unroll
      for (int ns = 0; ns < 4; ++ns) {
        bf16x8 pf = *(const bf16x8*)&Ph[s_base + ns * 16 + lr][ks * 32 + quad * 8];
        oacc[0][ns] = __builtin_amdgcn_mfma_f32_16x16x32_bf16(vh0, pf, oacc[0][ns], 0, 0, 0);
        oacc[0][ns] = __builtin_amdgcn_mfma_f32_16x16x32_bf16(vl0, pf, oacc[0][ns], 0, 0, 0);
        oacc[1][ns] = __builtin_amdgcn_mfma_f32_16x16x32_bf16(vh1, pf, oacc[1][ns], 0, 0, 0);
        oacc[1][ns] = __builtin_amdgcn_mfma_f32_16x16x32_bf16(vl1, pf, oacc[1][ns], 0, 0, 0);
      }
    }
  }

  // ---- l reduction across the 4 quads (lane keeps its own s = ns*16+lr) ----
  float invl[4];
  #pragma unroll
  for (int ns = 0; ns < 4; ++ns) {
    float v = lpart[ns];
    v += __shfl_xor(v, 16);
    v += __shfl_xor(v, 32);
    invl[ns] = 1.0f / v;
  }

  // ---- epilogue: gate + normalize, pack (hi|lo) bf16 in place over Gb ----
  #pragma unroll
  for (int ns = 0; ns < 4; ++ns) {
    const int s = s_base + ns * 16 + lr;
    float* gp = Gb + ((size_t)(s * I_DIM + i)) * TOTAL + h * HEAD_DIM;
    #pragma unroll
    for (int md = 0; md < 2; ++md) {
      const int d0 = md * 16 + quad * 4;
      float4 g = *(const float4*)(gp + d0);
      float o0 = g.x * oacc[md][ns][0] * invl[ns];
      float o1 = g.y * oacc[md][ns][1] * invl[ns];
      float o2 = g.z * oacc[md][ns][2] * invl[ns];
      float o3 = g.w * oacc[md][ns][3] * invl[ns];
      short h0 = f2bf(o0), h1 = f2bf(o1), h2 = f2bf(o2), h3 = f2bf(o3);
      uint4 pk;
      pk.x = (unsigned short)h0 | ((unsigned)(unsigned short)f2bf(o0 - bf2f(h0)) << 16);
      pk.y = (unsigned short)h1 | ((unsigned)(unsigned short)f2bf(o1 - bf2f(h1)) << 16);
      pk.z = (unsigned short)h2 | ((unsigned)(unsigned short)f2bf(o2 - bf2f(h2)) << 16);
      pk.w = (unsigned short)h3 | ((unsigned)(unsigned short)f2bf(o3 - bf2f(h3)) << 16);
      *(uint4*)(gp + d0) = pk;
    }
  }
}

// ---------------------------------------------------------------------------
// Kernel 4: output projection, split-bf16 MFMA (unchanged from R2).
// ---------------------------------------------------------------------------
__global__ __launch_bounds__(256) void out_kernel(
    const unsigned* __restrict__ Ap, const float* __restrict__ Wo,
    const float* __restrict__ bo, float* __restrict__ out) {
  __shared__ __align__(16) short Ah[128][40];
  __shared__ __align__(16) short Al[128][40];
  __shared__ __align__(16) short Bh[128][40];
  __shared__ __align__(16) short Bl[128][40];

  const int n0 = blockIdx.x * 128;
  const int r0 = blockIdx.y * 128;
  const int tid = threadIdx.x;
  const int wave = tid >> 6, lane = tid & 63;
  const int wm = wave >> 1, wn = wave & 1;
  const int lr = lane & 15, quad = lane >> 4;
  const int srow  = tid >> 1;
  const int shalf = tid & 1;

  f32x4 acc[4][4] = {};

  for (int k0 = 0; k0 < TOTAL; k0 += 32) {
    const int kb = k0 + shalf * 16;
    const unsigned* ap = Ap + (size_t)(r0 + srow) * TOTAL + kb;
    bf16x8 avh0, avh1, avl0, avl1;
    #pragma unroll
    for (int j = 0; j < 8; ++j) {
      unsigned w0 = ap[j];
      unsigned w1 = ap[j + 8];
      avh0[j] = (short)(w0 & 0xFFFFu); avl0[j] = (short)(w0 >> 16);
      avh1[j] = (short)(w1 & 0xFFFFu); avl1[j] = (short)(w1 >> 16);
    }
    const float* wp = Wo + (size_t)kb * C_S + n0 + srow;
    bf16x8 bvh0, bvh1, bvl0, bvl1;
    #pragma unroll
    for (int j = 0; j < 8; ++j) {
      float w0 = wp[(size_t)j * C_S];
      float w1 = wp[(size_t)(j + 8) * C_S];
      short h0 = f2bf(w0), h1 = f2bf(w1);
      bvh0[j] = h0; bvl0[j] = f2bf(w0 - bf2f(h0));
      bvh1[j] = h1; bvl1[j] = f2bf(w1 - bf2f(h1));
    }
    __syncthreads();
    *(bf16x8*)&Ah[srow][shalf * 16 + 0] = avh0;
    *(bf16x8*)&Ah[srow][shalf * 16 + 8] = avh1;
    *(bf16x8*)&Al[srow][shalf * 16 + 0] = avl0;
    *(bf16x8*)&Al[srow][shalf * 16 + 8] = avl1;
    *(bf16x8*)&Bh[srow][shalf * 16 + 0] = bvh0;
    *(bf16x8*)&Bh[srow][shalf * 16 + 8] = bvh1;
    *(bf16x8*)&Bl[srow][shalf * 16 + 0] = bvl0;
    *(bf16x8*)&Bl[srow][shalf * 16 + 8] = bvl1;
    __syncthreads();

    bf16x8 ah[4], al[4], bh[4], bl[4];
    #pragma unroll
    for (int mt = 0; mt < 4; ++mt) {
      ah[mt] = *(const bf16x8*)&Ah[wm * 64 + mt * 16 + lr][quad * 8];
      al[mt] = *(const bf16x8*)&Al[wm * 64 + mt * 16 + lr][quad * 8];
    }
    #pragma unroll
    for (int nt = 0; nt < 4; ++nt) {
      bh[nt] = *(const bf16x8*)&Bh[wn * 64 + nt * 16 + lr][quad * 8];
      bl[nt] = *(const bf16x8*)&Bl[wn * 64 + nt * 16 + lr][quad * 8];
    }
    #pragma unroll
    for (int mt = 0; mt < 4; ++mt)
      #pragma unroll
      for (int nt = 0; nt < 4; ++nt) {
        acc[mt][nt] = __builtin_amdgcn_mfma_f32_16x16x32_bf16(ah[mt], bh[nt], acc[mt][nt], 0, 0, 0);
        acc[mt][nt] = __builtin_amdgcn_mfma_f32_16x16x32_bf16(ah[mt], bl[nt], acc[mt][nt], 0, 0, 0);
        acc[mt][nt] = __builtin_amdgcn_mfma_f32_16x16x32_bf16(al[mt], bh[nt], acc[mt][nt], 0, 0, 0);
      }
  }

  #pragma unroll
  for (int nt = 0; nt < 4; ++nt) {
    const int col = n0 + wn * 64 + nt * 16 + lr;
    const float b = bo[col];
    #pragma unroll
    for (int mt = 0; mt < 4; ++mt)
      #pragma unroll
      for (int reg = 0; reg < 4; ++reg) {
        const int row = r0 + wm * 64 + mt * 16 + quad * 4 + reg;
        out[(size_t)row * C_S + col] = acc[mt][nt][reg] + b;
      }
  }
}

// ---------------------------------------------------------------------------
extern "C" void kernel_launch(void* const* d_in, const int* in_sizes, int n_in,
                              void* d_out, int out_size, void* d_ws, size_t ws_size,
                              hipStream_t stream) {
  const float* msa   = (const float*)d_in[0];
  const float* gamma = (const float*)d_in[1];
  const float* beta  = (const float*)d_in[2];
  const float* Wq    = (const float*)d_in[3];
  const float* Wk    = (const float*)d_in[4];
  const float* Wv    = (const float*)d_in[5];
  const float* Wg    = (const float*)d_in[6];
  const float* bg    = (const float*)d_in[7];
  const float* Wo    = (const float*)d_in[8];
  const float* bo    = (const float*)d_in[9];
  float* out = (float*)d_out;

  // Workspace: 4 bf16 planes (Q/K hi/lo) + V fp32 + G fp32 = 256 MiB exactly.
  const size_t PLANE = (size_t)NROWS * TOTAL;    // 16.78M elements
  ushort* Qhi = (ushort*)d_ws;
  ushort* Qlo = Qhi + PLANE;
  ushort* Khi = Qlo + PLANE;
  ushort* Klo = Khi + PLANE;
  float*  Vb  = (float*)(Klo + PLANE);           // (i,h,s,d) fp32
  float*  Gb  = Vb + PLANE;                      // (row,col): sigmoid fp32, then packed bf16 hi|lo
  float2* musig = (float2*)d_out;                // LN stats, dead before out_kernel

  ln_stats_kernel<<<NROWS / 4, 256, 0, stream>>>(msa, musig);
  proj_kernel<<<dim3(8, 512), 256, 0, stream>>>(msa, musig, gamma, beta,
                                                Wq, Wk, Wv, Wg, bg,
                                                Qhi, Qlo, Khi, Klo, Vb, Gb);
  attn_kernel<<<I_DIM * NUM_HEADS, 256, 0, stream>>>(Qhi, Qlo, Khi, Klo, Vb, Gb);
  out_kernel<<<dim3(2, 512), 256, 0, stream>>>((const unsigned*)Gb, Wo, bo, out);
}

// Round 4
// 493.662 us; speedup vs baseline: 2.4425x; 1.0559x over previous
//
#include <hip/hip_runtime.h>
#include <hip/hip_fp16.h>
#include <math.h>

#define C_S 256
#define NUM_HEADS 8
#define HEAD_DIM 32
#define TOTAL 256
#define S_DIM 256
#define I_DIM 256
#define NROWS (S_DIM * I_DIM)   // 65536
#define LN_EPS 1e-5f

typedef __attribute__((ext_vector_type(8))) short bf16x8;   // 8 bf16 = 4 VGPR
typedef __attribute__((ext_vector_type(4))) float f32x4;

__device__ __forceinline__ short f2bf(float x) {
  unsigned u = __float_as_uint(x);
  u += 0x7FFFu + ((u >> 16) & 1u);
  return (short)(u >> 16);
}
__device__ __forceinline__ float bf2f(short h) {
  return __uint_as_float(((unsigned)(unsigned short)h) << 16);
}
// async global->LDS, 16B per lane; lds base must be wave-uniform.
__device__ __forceinline__ void gl16(const void* g, void* l) {
  __builtin_amdgcn_global_load_lds(
      (const __attribute__((address_space(1))) unsigned*)g,
      (__attribute__((address_space(3))) unsigned*)l, 16, 0, 0);
}

// ---------------------------------------------------------------------------
// prep_w: split + transpose weights once. QKVG -> combined [1024][256] bf16
// hi/lo planes (row = mat*256+n, k contiguous); Wo -> [256][256] planes.
// ---------------------------------------------------------------------------
__global__ __launch_bounds__(256) void prep_w_kernel(
    const float* __restrict__ Wq, const float* __restrict__ Wk,
    const float* __restrict__ Wv, const float* __restrict__ Wg,
    const float* __restrict__ Wo,
    ushort* __restrict__ Wch, ushort* __restrict__ Wcl,
    ushort* __restrict__ Woh, ushort* __restrict__ Wol) {
  const int b = blockIdx.x;            // 0..1279
  const int mat = b >> 8, n = b & 255;
  const int k = threadIdx.x;
  const float* W = (mat == 0) ? Wq : (mat == 1) ? Wk
                  : (mat == 2) ? Wv : (mat == 3) ? Wg : Wo;
  float v = W[(size_t)k * 256 + n];
  short h = f2bf(v);
  short l = f2bf(v - bf2f(h));
  if (mat < 4) {
    size_t off = ((size_t)(mat * 256 + n)) * 256 + k;
    Wch[off] = (ushort)h; Wcl[off] = (ushort)l;
  } else {
    size_t off = (size_t)n * 256 + k;
    Woh[off] = (ushort)h; Wol[off] = (ushort)l;
  }
}

// ---------------------------------------------------------------------------
// prep_x: LN stats + apply + hi/lo split, once. One wave per row.
// X planes live in d_out (dead until out_kernel overwrites it).
// ---------------------------------------------------------------------------
__global__ __launch_bounds__(256) void prep_x_kernel(
    const float* __restrict__ msa, const float* __restrict__ gamma,
    const float* __restrict__ beta,
    ushort* __restrict__ Xh, ushort* __restrict__ Xl) {
  const int row  = blockIdx.x * 4 + (threadIdx.x >> 6);
  const int lane = threadIdx.x & 63;
  float4 v = ((const float4*)(msa + (size_t)row * C_S))[lane];
  float sum = v.x + v.y + v.z + v.w;
  float sq  = v.x*v.x + v.y*v.y + v.z*v.z + v.w*v.w;
  #pragma unroll
  for (int off = 1; off < 64; off <<= 1) {
    sum += __shfl_xor(sum, off);
    sq  += __shfl_xor(sq, off);
  }
  float mu = sum * (1.0f / 256.0f);
  float rs = rsqrtf(sq * (1.0f / 256.0f) - mu * mu + LN_EPS);
  float4 gv = ((const float4*)gamma)[lane];
  float4 bv = ((const float4*)beta)[lane];
  float x0 = (v.x - mu) * rs * gv.x + bv.x;
  float x1 = (v.y - mu) * rs * gv.y + bv.y;
  float x2 = (v.z - mu) * rs * gv.z + bv.z;
  float x3 = (v.w - mu) * rs * gv.w + bv.w;
  short h0 = f2bf(x0), h1 = f2bf(x1), h2 = f2bf(x2), h3 = f2bf(x3);
  ushort4 hh = make_ushort4((ushort)h0, (ushort)h1, (ushort)h2, (ushort)h3);
  ushort4 ll = make_ushort4((ushort)f2bf(x0 - bf2f(h0)), (ushort)f2bf(x1 - bf2f(h1)),
                            (ushort)f2bf(x2 - bf2f(h2)), (ushort)f2bf(x3 - bf2f(h3)));
  *(ushort4*)(Xh + (size_t)row * 256 + lane * 4) = hh;
  *(ushort4*)(Xl + (size_t)row * 256 + lane * 4) = ll;
}

// ---------------------------------------------------------------------------
// proj: pure split-bf16 GEMM. X(65536x256) @ Wc^T(1024x256 rows [n][k]).
// 128x128 tile, BK=32, global_load_lds staging, XOR-swizzled LDS chunks.
// Epilogue: Q (pre-scaled log2e/sqrt32) / K -> bf16 hi/lo planes (i,h,s,d);
// V fp32 (i,h,s,d); G -> fp16 sigmoid (row,col).
// ---------------------------------------------------------------------------
__global__ __launch_bounds__(256) void proj_kernel(
    const ushort* __restrict__ Xh, const ushort* __restrict__ Xl,
    const ushort* __restrict__ Wch, const ushort* __restrict__ Wcl,
    const float* __restrict__ bg,
    ushort* __restrict__ Qhi, ushort* __restrict__ Qlo,
    ushort* __restrict__ Khi, ushort* __restrict__ Klo,
    float* __restrict__ Vb, __half* __restrict__ Gh) {
  __shared__ __align__(16) ushort At_h[128 * 32];
  __shared__ __align__(16) ushort At_l[128 * 32];
  __shared__ __align__(16) ushort Bt_h[128 * 32];
  __shared__ __align__(16) ushort Bt_l[128 * 32];

  const int n0 = blockIdx.x * 128;               // combined col base (0..896)
  const int r0 = blockIdx.y * 128;
  const int tid = threadIdx.x;
  const int wave = tid >> 6, lane = tid & 63;
  const int wm = wave >> 1, wn = wave & 1;
  const int lr = lane & 15, quad = lane >> 4;
  const int fsw = (quad ^ ((lr >> 1) & 3)) * 8;  // fragment chunk offset (elems)

  // staging geometry: slot covers (row, 16B-chunk); swizzle chunk by row.
  const int slot = wave * 64 + lane;             // 0..255
  const int row0 = slot >> 2;                    // 0..63
  const int kc   = ((slot & 3) ^ ((row0 >> 1) & 3)) * 8;

  const ushort* pAh0 = Xh + (size_t)(r0 + row0) * 256 + kc;
  const ushort* pAh1 = Xh + (size_t)(r0 + row0 + 64) * 256 + kc;
  const ushort* pAl0 = Xl + (size_t)(r0 + row0) * 256 + kc;
  const ushort* pAl1 = Xl + (size_t)(r0 + row0 + 64) * 256 + kc;
  const ushort* pBh0 = Wch + (size_t)(n0 + row0) * 256 + kc;
  const ushort* pBh1 = Wch + (size_t)(n0 + row0 + 64) * 256 + kc;
  const ushort* pBl0 = Wcl + (size_t)(n0 + row0) * 256 + kc;
  const ushort* pBl1 = Wcl + (size_t)(n0 + row0 + 64) * 256 + kc;
  ushort* dst0 = (ushort*)nullptr;
  const int ld0 = wave * 512;                    // lds elem base, issue 1
  const int ld1 = 2048 + wave * 512;             // lds elem base, issue 2

  f32x4 acc[4][4] = {};

  for (int kk = 0; kk < 8; ++kk) {
    __syncthreads();                             // prev compute done with LDS
    gl16(pAh0, At_h + ld0); gl16(pAh1, At_h + ld1);
    gl16(pAl0, At_l + ld0); gl16(pAl1, At_l + ld1);
    gl16(pBh0, Bt_h + ld0); gl16(pBh1, Bt_h + ld1);
    gl16(pBl0, Bt_l + ld0); gl16(pBl1, Bt_l + ld1);
    pAh0 += 32; pAh1 += 32; pAl0 += 32; pAl1 += 32;
    pBh0 += 32; pBh1 += 32; pBl0 += 32; pBl1 += 32;
    __syncthreads();                             // drain vmcnt (loads landed)

    bf16x8 ah[4], al[4], bh[4], bl[4];
    #pragma unroll
    for (int mt = 0; mt < 4; ++mt) {
      const int off = (wm * 64 + mt * 16 + lr) * 32 + fsw;
      ah[mt] = *(const bf16x8*)&At_h[off];
      al[mt] = *(const bf16x8*)&At_l[off];
    }
    #pragma unroll
    for (int nt = 0; nt < 4; ++nt) {
      const int off = (wn * 64 + nt * 16 + lr) * 32 + fsw;
      bh[nt] = *(const bf16x8*)&Bt_h[off];
      bl[nt] = *(const bf16x8*)&Bt_l[off];
    }
    #pragma unroll
    for (int mt = 0; mt < 4; ++mt)
      #pragma unroll
      for (int nt = 0; nt < 4; ++nt) {
        acc[mt][nt] = __builtin_amdgcn_mfma_f32_16x16x32_bf16(ah[mt], bh[nt], acc[mt][nt], 0, 0, 0);
        acc[mt][nt] = __builtin_amdgcn_mfma_f32_16x16x32_bf16(ah[mt], bl[nt], acc[mt][nt], 0, 0, 0);
        acc[mt][nt] = __builtin_amdgcn_mfma_f32_16x16x32_bf16(al[mt], bh[nt], acc[mt][nt], 0, 0, 0);
      }
  }
  (void)dst0;

  // ---- epilogue ----
  const int region = blockIdx.x >> 1;            // 0:Q 1:K 2:V 3:G
  const int nb = (blockIdx.x & 1) * 128;
  if (region == 3) {
    #pragma unroll
    for (int nt = 0; nt < 4; ++nt) {
      const int lcol = nb + wn * 64 + nt * 16 + lr;
      const float b = bg[lcol];
      #pragma unroll
      for (int mt = 0; mt < 4; ++mt)
        #pragma unroll
        for (int reg = 0; reg < 4; ++reg) {
          const int row = r0 + wm * 64 + mt * 16 + quad * 4 + reg;
          float v = acc[mt][nt][reg] + b;
          Gh[(size_t)row * TOTAL + lcol] = __float2half(1.0f / (1.0f + __expf(-v)));
        }
    }
  } else if (region == 2) {
    #pragma unroll
    for (int nt = 0; nt < 4; ++nt) {
      const int lcol = nb + wn * 64 + nt * 16 + lr;
      const int h = lcol >> 5, d = lcol & 31;
      #pragma unroll
      for (int mt = 0; mt < 4; ++mt)
        #pragma unroll
        for (int reg = 0; reg < 4; ++reg) {
          const int row = r0 + wm * 64 + mt * 16 + quad * 4 + reg;
          const int s = row >> 8, i = row & 255;
          Vb[(((size_t)(i * NUM_HEADS + h)) * S_DIM + s) * HEAD_DIM + d] =
              acc[mt][nt][reg];
        }
    }
  } else {
    ushort* Phi = (region == 0) ? Qhi : Khi;
    ushort* Plo = (region == 0) ? Qlo : Klo;
    const float scale = (region == 0) ? 0.25503534f : 1.0f;  // log2e/sqrt(32)
    #pragma unroll
    for (int nt = 0; nt < 4; ++nt) {
      const int lcol = nb + wn * 64 + nt * 16 + lr;
      const int h = lcol >> 5, d = lcol & 31;
      #pragma unroll
      for (int mt = 0; mt < 4; ++mt)
        #pragma unroll
        for (int reg = 0; reg < 4; ++reg) {
          const int row = r0 + wm * 64 + mt * 16 + quad * 4 + reg;
          const int s = row >> 8, i = row & 255;
          float v = acc[mt][nt][reg] * scale;
          short hb = f2bf(v);
          size_t off = (((size_t)(i * NUM_HEADS + h)) * S_DIM + s) * HEAD_DIM + d;
          Phi[off] = (ushort)hb;
          Plo[off] = (ushort)f2bf(v - bf2f(hb));
        }
    }
  }
}

// ---------------------------------------------------------------------------
// attn: MFMA column attention per (i,h) (mainloop = R3, validated).
// G read as fp16; gated output written as bf16 hi/lo planes IN PLACE over
// Qhi/Qlo (each block touches only its own (i,h) slice; all Q reads precede
// writes within each wave; waves own disjoint s-ranges).
// ---------------------------------------------------------------------------
__global__ __launch_bounds__(256, 2) void attn_kernel(
    const ushort* Qhi, const ushort* Qlo,
    const ushort* __restrict__ Khi, const ushort* __restrict__ Klo,
    const float* __restrict__ Vb, const __half* __restrict__ Gh,
    ushort* Ohi, ushort* Olo) {
  __shared__ __align__(16) ushort Ph[256][72];
  __shared__ __align__(16) ushort Vth[32][264];
  __shared__ __align__(16) ushort Vtl[32][264];

  const int ih = blockIdx.x;
  const int i = ih >> 3, h = ih & 7;
  const int tid = threadIdx.x;
  const int wave = tid >> 6, lane = tid & 63;
  const int lr = lane & 15, quad = lane >> 4;
  const int s_base = wave * 64;
  const size_t hbase = (size_t)ih * (S_DIM * HEAD_DIM);

  {
    const float4* vp = (const float4*)(Vb + hbase + (size_t)tid * HEAD_DIM);
    #pragma unroll
    for (int j = 0; j < 8; ++j) {
      float4 v = vp[j];
      float vv[4] = {v.x, v.y, v.z, v.w};
      #pragma unroll
      for (int e = 0; e < 4; ++e) {
        short hh = f2bf(vv[e]);
        Vth[j * 4 + e][tid] = (ushort)hh;
        Vtl[j * 4 + e][tid] = (ushort)f2bf(vv[e] - bf2f(hh));
      }
    }
  }
  __syncthreads();

  bf16x8 qh[4], ql[4];
  #pragma unroll
  for (int ns = 0; ns < 4; ++ns) {
    size_t off = hbase + (size_t)(s_base + ns * 16 + lr) * HEAD_DIM + quad * 8;
    qh[ns] = *(const bf16x8*)(Qhi + off);
    ql[ns] = *(const bf16x8*)(Qlo + off);
  }

  f32x4 oacc[2][4] = {};
  float lpart[4] = {};

  #pragma unroll 1
  for (int c = 0; c < 4; ++c) {
    const int t0 = c * 64;
    bf16x8 kh[4], kl[4];
    #pragma unroll
    for (int mt = 0; mt < 4; ++mt) {
      size_t off = hbase + (size_t)(t0 + mt * 16 + lr) * HEAD_DIM + quad * 8;
      kh[mt] = *(const bf16x8*)(Khi + off);
      kl[mt] = *(const bf16x8*)(Klo + off);
    }
    #pragma unroll
    for (int mt = 0; mt < 4; ++mt) {
      #pragma unroll
      for (int ns = 0; ns < 4; ++ns) {
        f32x4 sc = {};
        sc = __builtin_amdgcn_mfma_f32_16x16x32_bf16(kh[mt], qh[ns], sc, 0, 0, 0);
        sc = __builtin_amdgcn_mfma_f32_16x16x32_bf16(kh[mt], ql[ns], sc, 0, 0, 0);
        sc = __builtin_amdgcn_mfma_f32_16x16x32_bf16(kl[mt], qh[ns], sc, 0, 0, 0);
        ushort4 pk;
        float p0 = exp2f(sc[0]), p1 = exp2f(sc[1]);
        float p2 = exp2f(sc[2]), p3 = exp2f(sc[3]);
        short b0 = f2bf(p0), b1 = f2bf(p1), b2 = f2bf(p2), b3 = f2bf(p3);
        pk.x = (ushort)b0; pk.y = (ushort)b1; pk.z = (ushort)b2; pk.w = (ushort)b3;
        lpart[ns] += (bf2f(b0) + bf2f(b1)) + (bf2f(b2) + bf2f(b3));
        const int srow = s_base + ns * 16 + lr;
        *(ushort4*)&Ph[srow][mt * 16 + quad * 4] = pk;
      }
    }
    #pragma unroll
    for (int ks = 0; ks < 2; ++ks) {
      const int tq = t0 + ks * 32 + quad * 8;
      bf16x8 vh0 = *(const bf16x8*)&Vth[lr][tq];
      bf16x8 vl0 = *(const bf16x8*)&Vtl[lr][tq];
      bf16x8 vh1 = *(const bf16x8*)&Vth[16 + lr][tq];
      bf16x8 vl1 = *(const bf16x8*)&Vtl[16 + lr][tq];
      #pragma unroll
      for (int ns = 0; ns < 4; ++ns) {
        bf16x8 pf = *(const bf16x8*)&Ph[s_base + ns * 16 + lr][ks * 32 + quad * 8];
        oacc[0][ns] = __builtin_amdgcn_mfma_f32_16x16x32_bf16(vh0, pf, oacc[0][ns], 0, 0, 0);
        oacc[0][ns] = __builtin_amdgcn_mfma_f32_16x16x32_bf16(vl0, pf, oacc[0][ns], 0, 0, 0);
        oacc[1][ns] = __builtin_amdgcn_mfma_f32_16x16x32_bf16(vh1, pf, oacc[1][ns], 0, 0, 0);
        oacc[1][ns] = __builtin_amdgcn_mfma_f32_16x16x32_bf16(vl1, pf, oacc[1][ns], 0, 0, 0);
      }
    }
  }

  float invl[4];
  #pragma unroll
  for (int ns = 0; ns < 4; ++ns) {
    float v = lpart[ns];
    v += __shfl_xor(v, 16);
    v += __shfl_xor(v, 32);
    invl[ns] = 1.0f / v;
  }

  #pragma unroll
  for (int ns = 0; ns < 4; ++ns) {
    const int s = s_base + ns * 16 + lr;
    const __half* gp = Gh + ((size_t)(s * I_DIM + i)) * TOTAL + h * HEAD_DIM;
    #pragma unroll
    for (int md = 0; md < 2; ++md) {
      const int d0 = md * 16 + quad * 4;
      float g0 = __half2float(gp[d0 + 0]);
      float g1 = __half2float(gp[d0 + 1]);
      float g2 = __half2float(gp[d0 + 2]);
      float g3 = __half2float(gp[d0 + 3]);
      float o0 = g0 * oacc[md][ns][0] * invl[ns];
      float o1 = g1 * oacc[md][ns][1] * invl[ns];
      float o2 = g2 * oacc[md][ns][2] * invl[ns];
      float o3 = g3 * oacc[md][ns][3] * invl[ns];
      short h0 = f2bf(o0), h1 = f2bf(o1), h2 = f2bf(o2), h3 = f2bf(o3);
      ushort4 hv = make_ushort4((ushort)h0, (ushort)h1, (ushort)h2, (ushort)h3);
      ushort4 lv = make_ushort4((ushort)f2bf(o0 - bf2f(h0)), (ushort)f2bf(o1 - bf2f(h1)),
                                (ushort)f2bf(o2 - bf2f(h2)), (ushort)f2bf(o3 - bf2f(h3)));
      *(ushort4*)(Ohi + hbase + (size_t)s * HEAD_DIM + d0) = hv;
      *(ushort4*)(Olo + hbase + (size_t)s * HEAD_DIM + d0) = lv;
    }
  }
}

// ---------------------------------------------------------------------------
// out: pure split-bf16 GEMM. A = O planes (i,h,s,d); B = Wo^T planes [n][k].
// m-tile = (s fixed, 128 i's); k-tile 32 = one head.
// ---------------------------------------------------------------------------
__global__ __launch_bounds__(256) void out_kernel(
    const ushort* __restrict__ Ohi, const ushort* __restrict__ Olo,
    const ushort* __restrict__ Woh, const ushort* __restrict__ Wol,
    const float* __restrict__ bo, float* __restrict__ out) {
  __shared__ __align__(16) ushort At_h[128 * 32];
  __shared__ __align__(16) ushort At_l[128 * 32];
  __shared__ __align__(16) ushort Bt_h[128 * 32];
  __shared__ __align__(16) ushort Bt_l[128 * 32];

  const int n0 = blockIdx.x * 128;
  const int s  = blockIdx.y >> 1;
  const int i0 = (blockIdx.y & 1) * 128;
  const int tid = threadIdx.x;
  const int wave = tid >> 6, lane = tid & 63;
  const int wm = wave >> 1, wn = wave & 1;
  const int lr = lane & 15, quad = lane >> 4;
  const int fsw = (quad ^ ((lr >> 1) & 3)) * 8;

  const int slot = wave * 64 + lane;
  const int row0 = slot >> 2;
  const int kc   = ((slot & 3) ^ ((row0 >> 1) & 3)) * 8;

  // A row = i; element (i, h, s, d): ((i*8+h)*256+s)*32 + d
  const ushort* pAh0 = Ohi + (size_t)(i0 + row0) * 65536 + (size_t)s * 32 + kc;
  const ushort* pAh1 = Ohi + (size_t)(i0 + row0 + 64) * 65536 + (size_t)s * 32 + kc;
  const ushort* pAl0 = Olo + (size_t)(i0 + row0) * 65536 + (size_t)s * 32 + kc;
  const ushort* pAl1 = Olo + (size_t)(i0 + row0 + 64) * 65536 + (size_t)s * 32 + kc;
  const ushort* pBh0 = Woh + (size_t)(n0 + row0) * 256 + kc;
  const ushort* pBh1 = Woh + (size_t)(n0 + row0 + 64) * 256 + kc;
  const ushort* pBl0 = Wol + (size_t)(n0 + row0) * 256 + kc;
  const ushort* pBl1 = Wol + (size_t)(n0 + row0 + 64) * 256 + kc;
  const int ld0 = wave * 512;
  const int ld1 = 2048 + wave * 512;

  f32x4 acc[4][4] = {};

  for (int kk = 0; kk < 8; ++kk) {
    __syncthreads();
    gl16(pAh0, At_h + ld0); gl16(pAh1, At_h + ld1);
    gl16(pAl0, At_l + ld0); gl16(pAl1, At_l + ld1);
    gl16(pBh0, Bt_h + ld0); gl16(pBh1, Bt_h + ld1);
    gl16(pBl0, Bt_l + ld0); gl16(pBl1, Bt_l + ld1);
    pAh0 += 8192; pAh1 += 8192; pAl0 += 8192; pAl1 += 8192;  // next head
    pBh0 += 32; pBh1 += 32; pBl0 += 32; pBl1 += 32;
    __syncthreads();

    bf16x8 ah[4], al[4], bh[4], bl[4];
    #pragma unroll
    for (int mt = 0; mt < 4; ++mt) {
      const int off = (wm * 64 + mt * 16 + lr) * 32 + fsw;
      ah[mt] = *(const bf16x8*)&At_h[off];
      al[mt] = *(const bf16x8*)&At_l[off];
    }
    #pragma unroll
    for (int nt = 0; nt < 4; ++nt) {
      const int off = (wn * 64 + nt * 16 + lr) * 32 + fsw;
      bh[nt] = *(const bf16x8*)&Bt_h[off];
      bl[nt] = *(const bf16x8*)&Bt_l[off];
    }
    #pragma unroll
    for (int mt = 0; mt < 4; ++mt)
      #pragma unroll
      for (int nt = 0; nt < 4; ++nt) {
        acc[mt][nt] = __builtin_amdgcn_mfma_f32_16x16x32_bf16(ah[mt], bh[nt], acc[mt][nt], 0, 0, 0);
        acc[mt][nt] = __builtin_amdgcn_mfma_f32_16x16x32_bf16(ah[mt], bl[nt], acc[mt][nt], 0, 0, 0);
        acc[mt][nt] = __builtin_amdgcn_mfma_f32_16x16x32_bf16(al[mt], bh[nt], acc[mt][nt], 0, 0, 0);
      }
  }

  #pragma unroll
  for (int nt = 0; nt < 4; ++nt) {
    const int col = n0 + wn * 64 + nt * 16 + lr;
    const float b = bo[col];
    #pragma unroll
    for (int mt = 0; mt < 4; ++mt)
      #pragma unroll
      for (int reg = 0; reg < 4; ++reg) {
        const int mloc = wm * 64 + mt * 16 + quad * 4 + reg;
        out[((size_t)s * 256 + i0 + mloc) * C_S + col] = acc[mt][nt][reg] + b;
      }
  }
}

// ---------------------------------------------------------------------------
extern "C" void kernel_launch(void* const* d_in, const int* in_sizes, int n_in,
                              void* d_out, int out_size, void* d_ws, size_t ws_size,
                              hipStream_t stream) {
  const float* msa   = (const float*)d_in[0];
  const float* gamma = (const float*)d_in[1];
  const float* beta  = (const float*)d_in[2];
  const float* Wq    = (const float*)d_in[3];
  const float* Wk    = (const float*)d_in[4];
  const float* Wv    = (const float*)d_in[5];
  const float* Wg    = (const float*)d_in[6];
  const float* bg    = (const float*)d_in[7];
  const float* Wo    = (const float*)d_in[8];
  const float* bo    = (const float*)d_in[9];
  float* out = (float*)d_out;

  const size_t PLANE = (size_t)NROWS * TOTAL;    // 16.78M elements
  // ws: Q/K planes (134.2MB) + V fp32 (67.1) + G fp16 (33.6) + W planes (1.3)
  //   = 236.2 MB  (proven budget >= 268 MB)
  ushort* Qhi = (ushort*)d_ws;
  ushort* Qlo = Qhi + PLANE;
  ushort* Khi = Qlo + PLANE;
  ushort* Klo = Khi + PLANE;
  float*  Vb  = (float*)(Klo + PLANE);
  __half* Gh  = (__half*)(Vb + PLANE);
  ushort* Wch = (ushort*)(Gh + PLANE);           // [1024][256]
  ushort* Wcl = Wch + 1024 * 256;
  ushort* Woh = Wcl + 1024 * 256;                // [256][256]
  ushort* Wol = Woh + 256 * 256;
  // X planes live in d_out (67.1MB, dead until out_kernel overwrites it)
  ushort* Xh = (ushort*)d_out;
  ushort* Xl = Xh + PLANE;

  prep_w_kernel<<<1280, 256, 0, stream>>>(Wq, Wk, Wv, Wg, Wo, Wch, Wcl, Woh, Wol);
  prep_x_kernel<<<NROWS / 4, 256, 0, stream>>>(msa, gamma, beta, Xh, Xl);
  proj_kernel<<<dim3(8, 512), 256, 0, stream>>>(Xh, Xl, Wch, Wcl, bg,
                                                Qhi, Qlo, Khi, Klo, Vb, Gh);
  attn_kernel<<<I_DIM * NUM_HEADS, 256, 0, stream>>>(Qhi, Qlo, Khi, Klo, Vb, Gh,
                                                     Qhi, Qlo);
  out_kernel<<<dim3(2, 512), 256, 0, stream>>>(Qhi, Qlo, Woh, Wol, bo, out);
}

// Round 5
// 484.772 us; speedup vs baseline: 2.4873x; 1.0183x over previous
//
#include <hip/hip_runtime.h>
#include <hip/hip_fp16.h>
#include <math.h>

#define C_S 256
#define NUM_HEADS 8
#define HEAD_DIM 32
#define TOTAL 256
#define S_DIM 256
#define I_DIM 256
#define NROWS (S_DIM * I_DIM)   // 65536
#define LN_EPS 1e-5f

typedef __attribute__((ext_vector_type(8))) short bf16x8;   // 8 bf16 = 4 VGPR
typedef __attribute__((ext_vector_type(4))) float f32x4;

__device__ __forceinline__ short f2bf(float x) {
  unsigned u = __float_as_uint(x);
  u += 0x7FFFu + ((u >> 16) & 1u);
  return (short)(u >> 16);
}
__device__ __forceinline__ float bf2f(short h) {
  return __uint_as_float(((unsigned)(unsigned short)h) << 16);
}
// async global->LDS, 16B per lane; lds base must be wave-uniform.
__device__ __forceinline__ void gl16(const void* g, void* l) {
  __builtin_amdgcn_global_load_lds(
      (const __attribute__((address_space(1))) unsigned*)g,
      (__attribute__((address_space(3))) unsigned*)l, 16, 0, 0);
}

// ---------------------------------------------------------------------------
// prep_w: split + transpose weights once. QKVG -> combined [1024][256] bf16
// hi/lo planes (row = mat*256+n, k contiguous); Wo -> [256][256] planes.
// ---------------------------------------------------------------------------
__global__ __launch_bounds__(256) void prep_w_kernel(
    const float* __restrict__ Wq, const float* __restrict__ Wk,
    const float* __restrict__ Wv, const float* __restrict__ Wg,
    const float* __restrict__ Wo,
    ushort* __restrict__ Wch, ushort* __restrict__ Wcl,
    ushort* __restrict__ Woh, ushort* __restrict__ Wol) {
  const int b = blockIdx.x;            // 0..1279
  const int mat = b >> 8, n = b & 255;
  const int k = threadIdx.x;
  const float* W = (mat == 0) ? Wq : (mat == 1) ? Wk
                  : (mat == 2) ? Wv : (mat == 3) ? Wg : Wo;
  float v = W[(size_t)k * 256 + n];
  short h = f2bf(v);
  short l = f2bf(v - bf2f(h));
  if (mat < 4) {
    size_t off = ((size_t)(mat * 256 + n)) * 256 + k;
    Wch[off] = (ushort)h; Wcl[off] = (ushort)l;
  } else {
    size_t off = (size_t)n * 256 + k;
    Woh[off] = (ushort)h; Wol[off] = (ushort)l;
  }
}

// ---------------------------------------------------------------------------
// prep_x: LN stats + apply + hi/lo split, once. One wave per row.
// X planes live in d_out (dead until out_kernel overwrites it).
// ---------------------------------------------------------------------------
__global__ __launch_bounds__(256) void prep_x_kernel(
    const float* __restrict__ msa, const float* __restrict__ gamma,
    const float* __restrict__ beta,
    ushort* __restrict__ Xh, ushort* __restrict__ Xl) {
  const int row  = blockIdx.x * 4 + (threadIdx.x >> 6);
  const int lane = threadIdx.x & 63;
  float4 v = ((const float4*)(msa + (size_t)row * C_S))[lane];
  float sum = v.x + v.y + v.z + v.w;
  float sq  = v.x*v.x + v.y*v.y + v.z*v.z + v.w*v.w;
  #pragma unroll
  for (int off = 1; off < 64; off <<= 1) {
    sum += __shfl_xor(sum, off);
    sq  += __shfl_xor(sq, off);
  }
  float mu = sum * (1.0f / 256.0f);
  float rs = rsqrtf(sq * (1.0f / 256.0f) - mu * mu + LN_EPS);
  float4 gv = ((const float4*)gamma)[lane];
  float4 bv = ((const float4*)beta)[lane];
  float x0 = (v.x - mu) * rs * gv.x + bv.x;
  float x1 = (v.y - mu) * rs * gv.y + bv.y;
  float x2 = (v.z - mu) * rs * gv.z + bv.z;
  float x3 = (v.w - mu) * rs * gv.w + bv.w;
  short h0 = f2bf(x0), h1 = f2bf(x1), h2 = f2bf(x2), h3 = f2bf(x3);
  ushort4 hh = make_ushort4((ushort)h0, (ushort)h1, (ushort)h2, (ushort)h3);
  ushort4 ll = make_ushort4((ushort)f2bf(x0 - bf2f(h0)), (ushort)f2bf(x1 - bf2f(h1)),
                            (ushort)f2bf(x2 - bf2f(h2)), (ushort)f2bf(x3 - bf2f(h3)));
  *(ushort4*)(Xh + (size_t)row * 256 + lane * 4) = hh;
  *(ushort4*)(Xl + (size_t)row * 256 + lane * 4) = ll;
}

// ---------------------------------------------------------------------------
// proj: pure split-bf16 GEMM. X(65536x256) @ Wc^T(1024x256 rows [n][k]).
// 128x128 tile, BK=32, global_load_lds staging, XOR-swizzled LDS chunks.
// Grid: 1D 4096, XCD-swizzled so the 8 n-tiles of one row-tile run
// back-to-back on ONE XCD -> X tile (256 KB) is fetched once into that
// XCD's L2 and reused by the other 7 blocks.
// ---------------------------------------------------------------------------
__global__ __launch_bounds__(256) void proj_kernel(
    const ushort* __restrict__ Xh, const ushort* __restrict__ Xl,
    const ushort* __restrict__ Wch, const ushort* __restrict__ Wcl,
    const float* __restrict__ bg,
    ushort* __restrict__ Qhi, ushort* __restrict__ Qlo,
    ushort* __restrict__ Khi, ushort* __restrict__ Klo,
    float* __restrict__ Vb, __half* __restrict__ Gh) {
  __shared__ __align__(16) ushort At_h[128 * 32];
  __shared__ __align__(16) ushort At_l[128 * 32];
  __shared__ __align__(16) ushort Bt_h[128 * 32];
  __shared__ __align__(16) ushort Bt_l[128 * 32];

  // XCD swizzle: xcd = bid&7 (dispatch round-robins XCDs), j = bid>>3.
  // ntile varies fastest within an XCD -> same row-tile 8x in a row.
  const int bid = blockIdx.x;
  const int xcd = bid & 7;
  const int j   = bid >> 3;
  const int ntile = j & 7;                       // 0..7 over the 1024 cols
  const int rt    = (xcd << 6) + (j >> 3);       // 0..511 row tile
  const int n0 = ntile * 128;
  const int r0 = rt * 128;
  const int tid = threadIdx.x;
  const int wave = tid >> 6, lane = tid & 63;
  const int wm = wave >> 1, wn = wave & 1;
  const int lr = lane & 15, quad = lane >> 4;
  const int fsw = (quad ^ ((lr >> 1) & 3)) * 8;  // fragment chunk offset (elems)

  // staging geometry: slot covers (row, 16B-chunk); swizzle chunk by row.
  const int slot = wave * 64 + lane;             // 0..255
  const int row0 = slot >> 2;                    // 0..63
  const int kc   = ((slot & 3) ^ ((row0 >> 1) & 3)) * 8;

  const ushort* pAh0 = Xh + (size_t)(r0 + row0) * 256 + kc;
  const ushort* pAh1 = Xh + (size_t)(r0 + row0 + 64) * 256 + kc;
  const ushort* pAl0 = Xl + (size_t)(r0 + row0) * 256 + kc;
  const ushort* pAl1 = Xl + (size_t)(r0 + row0 + 64) * 256 + kc;
  const ushort* pBh0 = Wch + (size_t)(n0 + row0) * 256 + kc;
  const ushort* pBh1 = Wch + (size_t)(n0 + row0 + 64) * 256 + kc;
  const ushort* pBl0 = Wcl + (size_t)(n0 + row0) * 256 + kc;
  const ushort* pBl1 = Wcl + (size_t)(n0 + row0 + 64) * 256 + kc;
  const int ld0 = wave * 512;                    // lds elem base, issue 1
  const int ld1 = 2048 + wave * 512;             // lds elem base, issue 2

  f32x4 acc[4][4] = {};

  for (int kk = 0; kk < 8; ++kk) {
    __syncthreads();                             // prev compute done with LDS
    gl16(pAh0, At_h + ld0); gl16(pAh1, At_h + ld1);
    gl16(pAl0, At_l + ld0); gl16(pAl1, At_l + ld1);
    gl16(pBh0, Bt_h + ld0); gl16(pBh1, Bt_h + ld1);
    gl16(pBl0, Bt_l + ld0); gl16(pBl1, Bt_l + ld1);
    pAh0 += 32; pAh1 += 32; pAl0 += 32; pAl1 += 32;
    pBh0 += 32; pBh1 += 32; pBl0 += 32; pBl1 += 32;
    __syncthreads();                             // drain vmcnt (loads landed)

    bf16x8 ah[4], al[4], bh[4], bl[4];
    #pragma unroll
    for (int mt = 0; mt < 4; ++mt) {
      const int off = (wm * 64 + mt * 16 + lr) * 32 + fsw;
      ah[mt] = *(const bf16x8*)&At_h[off];
      al[mt] = *(const bf16x8*)&At_l[off];
    }
    #pragma unroll
    for (int nt = 0; nt < 4; ++nt) {
      const int off = (wn * 64 + nt * 16 + lr) * 32 + fsw;
      bh[nt] = *(const bf16x8*)&Bt_h[off];
      bl[nt] = *(const bf16x8*)&Bt_l[off];
    }
    #pragma unroll
    for (int mt = 0; mt < 4; ++mt)
      #pragma unroll
      for (int nt = 0; nt < 4; ++nt) {
        acc[mt][nt] = __builtin_amdgcn_mfma_f32_16x16x32_bf16(ah[mt], bh[nt], acc[mt][nt], 0, 0, 0);
        acc[mt][nt] = __builtin_amdgcn_mfma_f32_16x16x32_bf16(ah[mt], bl[nt], acc[mt][nt], 0, 0, 0);
        acc[mt][nt] = __builtin_amdgcn_mfma_f32_16x16x32_bf16(al[mt], bh[nt], acc[mt][nt], 0, 0, 0);
      }
  }

  // ---- epilogue ----
  const int region = ntile >> 1;                 // 0:Q 1:K 2:V 3:G
  const int nb = (ntile & 1) * 128;
  if (region == 3) {
    #pragma unroll
    for (int nt = 0; nt < 4; ++nt) {
      const int lcol = nb + wn * 64 + nt * 16 + lr;
      const float b = bg[lcol];
      #pragma unroll
      for (int mt = 0; mt < 4; ++mt)
        #pragma unroll
        for (int reg = 0; reg < 4; ++reg) {
          const int row = r0 + wm * 64 + mt * 16 + quad * 4 + reg;
          float v = acc[mt][nt][reg] + b;
          Gh[(size_t)row * TOTAL + lcol] = __float2half(1.0f / (1.0f + __expf(-v)));
        }
    }
  } else if (region == 2) {
    #pragma unroll
    for (int nt = 0; nt < 4; ++nt) {
      const int lcol = nb + wn * 64 + nt * 16 + lr;
      const int h = lcol >> 5, d = lcol & 31;
      #pragma unroll
      for (int mt = 0; mt < 4; ++mt)
        #pragma unroll
        for (int reg = 0; reg < 4; ++reg) {
          const int row = r0 + wm * 64 + mt * 16 + quad * 4 + reg;
          const int s = row >> 8, i = row & 255;
          Vb[(((size_t)(i * NUM_HEADS + h)) * S_DIM + s) * HEAD_DIM + d] =
              acc[mt][nt][reg];
        }
    }
  } else {
    ushort* Phi = (region == 0) ? Qhi : Khi;
    ushort* Plo = (region == 0) ? Qlo : Klo;
    const float scale = (region == 0) ? 0.25503534f : 1.0f;  // log2e/sqrt(32)
    #pragma unroll
    for (int nt = 0; nt < 4; ++nt) {
      const int lcol = nb + wn * 64 + nt * 16 + lr;
      const int h = lcol >> 5, d = lcol & 31;
      #pragma unroll
      for (int mt = 0; mt < 4; ++mt)
        #pragma unroll
        for (int reg = 0; reg < 4; ++reg) {
          const int row = r0 + wm * 64 + mt * 16 + quad * 4 + reg;
          const int s = row >> 8, i = row & 255;
          float v = acc[mt][nt][reg] * scale;
          short hb = f2bf(v);
          size_t off = (((size_t)(i * NUM_HEADS + h)) * S_DIM + s) * HEAD_DIM + d;
          Phi[off] = (ushort)hb;
          Plo[off] = (ushort)f2bf(v - bf2f(hb));
        }
    }
  }
}

// ---------------------------------------------------------------------------
// attn: MFMA column attention per (i,h) (mainloop = R3, validated).
// G read as fp16; gated output written as bf16 hi/lo planes IN PLACE over
// Qhi/Qlo (each block touches only its own (i,h) slice; all Q reads precede
// writes within each wave; waves own disjoint s-ranges).
// ---------------------------------------------------------------------------
__global__ __launch_bounds__(256, 2) void attn_kernel(
    const ushort* Qhi, const ushort* Qlo,
    const ushort* __restrict__ Khi, const ushort* __restrict__ Klo,
    const float* __restrict__ Vb, const __half* __restrict__ Gh,
    ushort* Ohi, ushort* Olo) {
  __shared__ __align__(16) ushort Ph[256][72];
  __shared__ __align__(16) ushort Vth[32][264];
  __shared__ __align__(16) ushort Vtl[32][264];

  const int ih = blockIdx.x;
  const int i = ih >> 3, h = ih & 7;
  const int tid = threadIdx.x;
  const int wave = tid >> 6, lane = tid & 63;
  const int lr = lane & 15, quad = lane >> 4;
  const int s_base = wave * 64;
  const size_t hbase = (size_t)ih * (S_DIM * HEAD_DIM);

  {
    const float4* vp = (const float4*)(Vb + hbase + (size_t)tid * HEAD_DIM);
    #pragma unroll
    for (int j = 0; j < 8; ++j) {
      float4 v = vp[j];
      float vv[4] = {v.x, v.y, v.z, v.w};
      #pragma unroll
      for (int e = 0; e < 4; ++e) {
        short hh = f2bf(vv[e]);
        Vth[j * 4 + e][tid] = (ushort)hh;
        Vtl[j * 4 + e][tid] = (ushort)f2bf(vv[e] - bf2f(hh));
      }
    }
  }
  __syncthreads();

  bf16x8 qh[4], ql[4];
  #pragma unroll
  for (int ns = 0; ns < 4; ++ns) {
    size_t off = hbase + (size_t)(s_base + ns * 16 + lr) * HEAD_DIM + quad * 8;
    qh[ns] = *(const bf16x8*)(Qhi + off);
    ql[ns] = *(const bf16x8*)(Qlo + off);
  }

  f32x4 oacc[2][4] = {};
  float lpart[4] = {};

  #pragma unroll 1
  for (int c = 0; c < 4; ++c) {
    const int t0 = c * 64;
    bf16x8 kh[4], kl[4];
    #pragma unroll
    for (int mt = 0; mt < 4; ++mt) {
      size_t off = hbase + (size_t)(t0 + mt * 16 + lr) * HEAD_DIM + quad * 8;
      kh[mt] = *(const bf16x8*)(Khi + off);
      kl[mt] = *(const bf16x8*)(Klo + off);
    }
    #pragma unroll
    for (int mt = 0; mt < 4; ++mt) {
      #pragma unroll
      for (int ns = 0; ns < 4; ++ns) {
        f32x4 sc = {};
        sc = __builtin_amdgcn_mfma_f32_16x16x32_bf16(kh[mt], qh[ns], sc, 0, 0, 0);
        sc = __builtin_amdgcn_mfma_f32_16x16x32_bf16(kh[mt], ql[ns], sc, 0, 0, 0);
        sc = __builtin_amdgcn_mfma_f32_16x16x32_bf16(kl[mt], qh[ns], sc, 0, 0, 0);
        ushort4 pk;
        float p0 = exp2f(sc[0]), p1 = exp2f(sc[1]);
        float p2 = exp2f(sc[2]), p3 = exp2f(sc[3]);
        short b0 = f2bf(p0), b1 = f2bf(p1), b2 = f2bf(p2), b3 = f2bf(p3);
        pk.x = (ushort)b0; pk.y = (ushort)b1; pk.z = (ushort)b2; pk.w = (ushort)b3;
        lpart[ns] += (bf2f(b0) + bf2f(b1)) + (bf2f(b2) + bf2f(b3));
        const int srow = s_base + ns * 16 + lr;
        *(ushort4*)&Ph[srow][mt * 16 + quad * 4] = pk;
      }
    }
    #pragma unroll
    for (int ks = 0; ks < 2; ++ks) {
      const int tq = t0 + ks * 32 + quad * 8;
      bf16x8 vh0 = *(const bf16x8*)&Vth[lr][tq];
      bf16x8 vl0 = *(const bf16x8*)&Vtl[lr][tq];
      bf16x8 vh1 = *(const bf16x8*)&Vth[16 + lr][tq];
      bf16x8 vl1 = *(const bf16x8*)&Vtl[16 + lr][tq];
      #pragma unroll
      for (int ns = 0; ns < 4; ++ns) {
        bf16x8 pf = *(const bf16x8*)&Ph[s_base + ns * 16 + lr][ks * 32 + quad * 8];
        oacc[0][ns] = __builtin_amdgcn_mfma_f32_16x16x32_bf16(vh0, pf, oacc[0][ns], 0, 0, 0);
        oacc[0][ns] = __builtin_amdgcn_mfma_f32_16x16x32_bf16(vl0, pf, oacc[0][ns], 0, 0, 0);
        oacc[1][ns] = __builtin_amdgcn_mfma_f32_16x16x32_bf16(vh1, pf, oacc[1][ns], 0, 0, 0);
        oacc[1][ns] = __builtin_amdgcn_mfma_f32_16x16x32_bf16(vl1, pf, oacc[1][ns], 0, 0, 0);
      }
    }
  }

  float invl[4];
  #pragma unroll
  for (int ns = 0; ns < 4; ++ns) {
    float v = lpart[ns];
    v += __shfl_xor(v, 16);
    v += __shfl_xor(v, 32);
    invl[ns] = 1.0f / v;
  }

  #pragma unroll
  for (int ns = 0; ns < 4; ++ns) {
    const int s = s_base + ns * 16 + lr;
    const __half* gp = Gh + ((size_t)(s * I_DIM + i)) * TOTAL + h * HEAD_DIM;
    #pragma unroll
    for (int md = 0; md < 2; ++md) {
      const int d0 = md * 16 + quad * 4;
      float g0 = __half2float(gp[d0 + 0]);
      float g1 = __half2float(gp[d0 + 1]);
      float g2 = __half2float(gp[d0 + 2]);
      float g3 = __half2float(gp[d0 + 3]);
      float o0 = g0 * oacc[md][ns][0] * invl[ns];
      float o1 = g1 * oacc[md][ns][1] * invl[ns];
      float o2 = g2 * oacc[md][ns][2] * invl[ns];
      float o3 = g3 * oacc[md][ns][3] * invl[ns];
      short h0 = f2bf(o0), h1 = f2bf(o1), h2 = f2bf(o2), h3 = f2bf(o3);
      ushort4 hv = make_ushort4((ushort)h0, (ushort)h1, (ushort)h2, (ushort)h3);
      ushort4 lv = make_ushort4((ushort)f2bf(o0 - bf2f(h0)), (ushort)f2bf(o1 - bf2f(h1)),
                                (ushort)f2bf(o2 - bf2f(h2)), (ushort)f2bf(o3 - bf2f(h3)));
      *(ushort4*)(Ohi + hbase + (size_t)s * HEAD_DIM + d0) = hv;
      *(ushort4*)(Olo + hbase + (size_t)s * HEAD_DIM + d0) = lv;
    }
  }
}

// ---------------------------------------------------------------------------
// out: pure split-bf16 GEMM. A = O planes (i,h,s,d); B = Wo^T planes [n][k].
// m-tile = (s fixed, 128 i's); k-tile 32 = one head. XCD-swizzled grid so
// the 2 n-tiles sharing an A row-tile run on one XCD.
// ---------------------------------------------------------------------------
__global__ __launch_bounds__(256) void out_kernel(
    const ushort* __restrict__ Ohi, const ushort* __restrict__ Olo,
    const ushort* __restrict__ Woh, const ushort* __restrict__ Wol,
    const float* __restrict__ bo, float* __restrict__ out) {
  __shared__ __align__(16) ushort At_h[128 * 32];
  __shared__ __align__(16) ushort At_l[128 * 32];
  __shared__ __align__(16) ushort Bt_h[128 * 32];
  __shared__ __align__(16) ushort Bt_l[128 * 32];

  const int bid = blockIdx.x;                    // 0..1023
  const int xcd = bid & 7;
  const int j   = bid >> 3;                      // 0..127
  const int ntile = j & 1;
  const int rg    = (xcd << 6) + (j >> 1);       // 0..511
  const int n0 = ntile * 128;
  const int s  = rg >> 1;
  const int i0 = (rg & 1) * 128;
  const int tid = threadIdx.x;
  const int wave = tid >> 6, lane = tid & 63;
  const int wm = wave >> 1, wn = wave & 1;
  const int lr = lane & 15, quad = lane >> 4;
  const int fsw = (quad ^ ((lr >> 1) & 3)) * 8;

  const int slot = wave * 64 + lane;
  const int row0 = slot >> 2;
  const int kc   = ((slot & 3) ^ ((row0 >> 1) & 3)) * 8;

  // A row = i; element (i, h, s, d): ((i*8+h)*256+s)*32 + d
  const ushort* pAh0 = Ohi + (size_t)(i0 + row0) * 65536 + (size_t)s * 32 + kc;
  const ushort* pAh1 = Ohi + (size_t)(i0 + row0 + 64) * 65536 + (size_t)s * 32 + kc;
  const ushort* pAl0 = Olo + (size_t)(i0 + row0) * 65536 + (size_t)s * 32 + kc;
  const ushort* pAl1 = Olo + (size_t)(i0 + row0 + 64) * 65536 + (size_t)s * 32 + kc;
  const ushort* pBh0 = Woh + (size_t)(n0 + row0) * 256 + kc;
  const ushort* pBh1 = Woh + (size_t)(n0 + row0 + 64) * 256 + kc;
  const ushort* pBl0 = Wol + (size_t)(n0 + row0) * 256 + kc;
  const ushort* pBl1 = Wol + (size_t)(n0 + row0 + 64) * 256 + kc;
  const int ld0 = wave * 512;
  const int ld1 = 2048 + wave * 512;

  f32x4 acc[4][4] = {};

  for (int kk = 0; kk < 8; ++kk) {
    __syncthreads();
    gl16(pAh0, At_h + ld0); gl16(pAh1, At_h + ld1);
    gl16(pAl0, At_l + ld0); gl16(pAl1, At_l + ld1);
    gl16(pBh0, Bt_h + ld0); gl16(pBh1, Bt_h + ld1);
    gl16(pBl0, Bt_l + ld0); gl16(pBl1, Bt_l + ld1);
    pAh0 += 8192; pAh1 += 8192; pAl0 += 8192; pAl1 += 8192;  // next head
    pBh0 += 32; pBh1 += 32; pBl0 += 32; pBl1 += 32;
    __syncthreads();

    bf16x8 ah[4], al[4], bh[4], bl[4];
    #pragma unroll
    for (int mt = 0; mt < 4; ++mt) {
      const int off = (wm * 64 + mt * 16 + lr) * 32 + fsw;
      ah[mt] = *(const bf16x8*)&At_h[off];
      al[mt] = *(const bf16x8*)&At_l[off];
    }
    #pragma unroll
    for (int nt = 0; nt < 4; ++nt) {
      const int off = (wn * 64 + nt * 16 + lr) * 32 + fsw;
      bh[nt] = *(const bf16x8*)&Bt_h[off];
      bl[nt] = *(const bf16x8*)&Bt_l[off];
    }
    #pragma unroll
    for (int mt = 0; mt < 4; ++mt)
      #pragma unroll
      for (int nt = 0; nt < 4; ++nt) {
        acc[mt][nt] = __builtin_amdgcn_mfma_f32_16x16x32_bf16(ah[mt], bh[nt], acc[mt][nt], 0, 0, 0);
        acc[mt][nt] = __builtin_amdgcn_mfma_f32_16x16x32_bf16(ah[mt], bl[nt], acc[mt][nt], 0, 0, 0);
        acc[mt][nt] = __builtin_amdgcn_mfma_f32_16x16x32_bf16(al[mt], bh[nt], acc[mt][nt], 0, 0, 0);
      }
  }

  #pragma unroll
  for (int nt = 0; nt < 4; ++nt) {
    const int col = n0 + wn * 64 + nt * 16 + lr;
    const float b = bo[col];
    #pragma unroll
    for (int mt = 0; mt < 4; ++mt)
      #pragma unroll
      for (int reg = 0; reg < 4; ++reg) {
        const int mloc = wm * 64 + mt * 16 + quad * 4 + reg;
        out[((size_t)s * 256 + i0 + mloc) * C_S + col] = acc[mt][nt][reg] + b;
      }
  }
}

// ---------------------------------------------------------------------------
extern "C" void kernel_launch(void* const* d_in, const int* in_sizes, int n_in,
                              void* d_out, int out_size, void* d_ws, size_t ws_size,
                              hipStream_t stream) {
  const float* msa   = (const float*)d_in[0];
  const float* gamma = (const float*)d_in[1];
  const float* beta  = (const float*)d_in[2];
  const float* Wq    = (const float*)d_in[3];
  const float* Wk    = (const float*)d_in[4];
  const float* Wv    = (const float*)d_in[5];
  const float* Wg    = (const float*)d_in[6];
  const float* bg    = (const float*)d_in[7];
  const float* Wo    = (const float*)d_in[8];
  const float* bo    = (const float*)d_in[9];
  float* out = (float*)d_out;

  const size_t PLANE = (size_t)NROWS * TOTAL;    // 16.78M elements
  // ws: Q/K planes (134.2MB) + V fp32 (67.1) + G fp16 (33.6) + W planes (1.3)
  ushort* Qhi = (ushort*)d_ws;
  ushort* Qlo = Qhi + PLANE;
  ushort* Khi = Qlo + PLANE;
  ushort* Klo = Khi + PLANE;
  float*  Vb  = (float*)(Klo + PLANE);
  __half* Gh  = (__half*)(Vb + PLANE);
  ushort* Wch = (ushort*)(Gh + PLANE);           // [1024][256]
  ushort* Wcl = Wch + 1024 * 256;
  ushort* Woh = Wcl + 1024 * 256;                // [256][256]
  ushort* Wol = Woh + 256 * 256;
  // X planes live in d_out (67.1MB, dead until out_kernel overwrites it)
  ushort* Xh = (ushort*)d_out;
  ushort* Xl = Xh + PLANE;

  prep_w_kernel<<<1280, 256, 0, stream>>>(Wq, Wk, Wv, Wg, Wo, Wch, Wcl, Woh, Wol);
  prep_x_kernel<<<NROWS / 4, 256, 0, stream>>>(msa, gamma, beta, Xh, Xl);
  proj_kernel<<<4096, 256, 0, stream>>>(Xh, Xl, Wch, Wcl, bg,
                                        Qhi, Qlo, Khi, Klo, Vb, Gh);
  attn_kernel<<<I_DIM * NUM_HEADS, 256, 0, stream>>>(Qhi, Qlo, Khi, Klo, Vb, Gh,
                                                     Qhi, Qlo);
  out_kernel<<<1024, 256, 0, stream>>>(Qhi, Qlo, Woh, Wol, bo, out);
}

// Round 6
// 308.661 us; speedup vs baseline: 3.9065x; 1.5706x over previous
//
#include <hip/hip_runtime.h>
#include <hip/hip_fp16.h>
#include <math.h>

#define C_S 256
#define NUM_HEADS 8
#define HEAD_DIM 32
#define TOTAL 256
#define S_DIM 256
#define I_DIM 256
#define NROWS (S_DIM * I_DIM)   // 65536
#define LN_EPS 1e-5f

typedef _Float16 f16x8 __attribute__((ext_vector_type(8)));   // 8 fp16 = 4 VGPR
typedef __attribute__((ext_vector_type(4))) float f32x4;

__device__ __forceinline__ ushort f2h(float x) {
  return __half_as_ushort(__float2half(x));      // RNE
}
__device__ __forceinline__ float h2f(ushort u) {
  return __half2float(__ushort_as_half(u));
}
// async global->LDS, 16B per lane; lds base must be wave-uniform.
__device__ __forceinline__ void gl16(const void* g, void* l) {
  __builtin_amdgcn_global_load_lds(
      (const __attribute__((address_space(1))) unsigned*)g,
      (__attribute__((address_space(3))) unsigned*)l, 16, 0, 0);
}

// ---------------------------------------------------------------------------
// prep_w: transpose + fp16-convert weights once.
// QKVG -> combined [1024][256] fp16 (row = mat*256+n, k contiguous);
// Wo -> [256][256] fp16.
// ---------------------------------------------------------------------------
__global__ __launch_bounds__(256) void prep_w_kernel(
    const float* __restrict__ Wq, const float* __restrict__ Wk,
    const float* __restrict__ Wv, const float* __restrict__ Wg,
    const float* __restrict__ Wo,
    ushort* __restrict__ Wch, ushort* __restrict__ Woh) {
  const int b = blockIdx.x;            // 0..1279
  const int mat = b >> 8, n = b & 255;
  const int k = threadIdx.x;
  const float* W = (mat == 0) ? Wq : (mat == 1) ? Wk
                  : (mat == 2) ? Wv : (mat == 3) ? Wg : Wo;
  ushort h = f2h(W[(size_t)k * 256 + n]);
  if (mat < 4) Wch[((size_t)(mat * 256 + n)) * 256 + k] = h;
  else         Woh[(size_t)n * 256 + k] = h;
}

// ---------------------------------------------------------------------------
// prep_x: LN stats + apply + fp16-convert, once. One wave per row.
// X fp16 lives in d_out (dead until out_kernel overwrites it).
// ---------------------------------------------------------------------------
__global__ __launch_bounds__(256) void prep_x_kernel(
    const float* __restrict__ msa, const float* __restrict__ gamma,
    const float* __restrict__ beta, ushort* __restrict__ Xh) {
  const int row  = blockIdx.x * 4 + (threadIdx.x >> 6);
  const int lane = threadIdx.x & 63;
  float4 v = ((const float4*)(msa + (size_t)row * C_S))[lane];
  float sum = v.x + v.y + v.z + v.w;
  float sq  = v.x*v.x + v.y*v.y + v.z*v.z + v.w*v.w;
  #pragma unroll
  for (int off = 1; off < 64; off <<= 1) {
    sum += __shfl_xor(sum, off);
    sq  += __shfl_xor(sq, off);
  }
  float mu = sum * (1.0f / 256.0f);
  float rs = rsqrtf(sq * (1.0f / 256.0f) - mu * mu + LN_EPS);
  float4 gv = ((const float4*)gamma)[lane];
  float4 bv = ((const float4*)beta)[lane];
  ushort4 hh;
  hh.x = f2h((v.x - mu) * rs * gv.x + bv.x);
  hh.y = f2h((v.y - mu) * rs * gv.y + bv.y);
  hh.z = f2h((v.z - mu) * rs * gv.z + bv.z);
  hh.w = f2h((v.w - mu) * rs * gv.w + bv.w);
  *(ushort4*)(Xh + (size_t)row * 256 + lane * 4) = hh;
}

// ---------------------------------------------------------------------------
// proj: pure fp16 GEMM. X(65536x256) @ Wc^T(1024 rows [n][k]).
// 128x128 tile, BK=64 as two proven-swizzle 32-wide sub-stages, 32KB LDS,
// global_load_lds staging, XCD-swizzled grid (X tile L2-resident per XCD).
// Epilogue: Q (pre-scaled log2e/sqrt32) / K / V fp16 (i,h,s,d); G fp16 sigmoid.
// ---------------------------------------------------------------------------
__global__ __launch_bounds__(256) void proj_kernel(
    const ushort* __restrict__ Xh, const ushort* __restrict__ Wch,
    const float* __restrict__ bg,
    ushort* __restrict__ Qh, ushort* __restrict__ Kh,
    ushort* __restrict__ Vh, __half* __restrict__ Gh) {
  __shared__ __align__(16) ushort At0[128 * 32];
  __shared__ __align__(16) ushort At1[128 * 32];
  __shared__ __align__(16) ushort Bt0[128 * 32];
  __shared__ __align__(16) ushort Bt1[128 * 32];

  const int bid = blockIdx.x;
  const int xcd = bid & 7;
  const int j   = bid >> 3;
  const int ntile = j & 7;                       // 0..7 over the 1024 cols
  const int rt    = (xcd << 6) + (j >> 3);       // 0..511 row tile
  const int n0 = ntile * 128;
  const int r0 = rt * 128;
  const int tid = threadIdx.x;
  const int wave = tid >> 6, lane = tid & 63;
  const int wm = wave >> 1, wn = wave & 1;
  const int lr = lane & 15, quad = lane >> 4;
  const int fsw = (quad ^ ((lr >> 1) & 3)) * 8;  // fragment chunk swizzle

  const int slot = wave * 64 + lane;
  const int row0 = slot >> 2;                    // 0..63
  const int kc   = ((slot & 3) ^ ((row0 >> 1) & 3)) * 8;

  const ushort* pA = Xh + (size_t)(r0 + row0) * 256 + kc;
  const ushort* pB = Wch + (size_t)(n0 + row0) * 256 + kc;
  const int ld0 = wave * 512;
  const int ld1 = 2048 + wave * 512;

  f32x4 acc[4][4] = {};

  for (int kk = 0; kk < 4; ++kk) {
    __syncthreads();                             // prev compute done with LDS
    gl16(pA,             At0 + ld0); gl16(pA + 64 * 256,      At0 + ld1);
    gl16(pA + 32,        At1 + ld0); gl16(pA + 64 * 256 + 32, At1 + ld1);
    gl16(pB,             Bt0 + ld0); gl16(pB + 64 * 256,      Bt0 + ld1);
    gl16(pB + 32,        Bt1 + ld0); gl16(pB + 64 * 256 + 32, Bt1 + ld1);
    pA += 64; pB += 64;
    __syncthreads();                             // vmcnt drain: loads landed

    f16x8 a0[4], a1[4], b0[4], b1[4];
    #pragma unroll
    for (int mt = 0; mt < 4; ++mt) {
      const int off = (wm * 64 + mt * 16 + lr) * 32 + fsw;
      a0[mt] = *(const f16x8*)&At0[off];
      a1[mt] = *(const f16x8*)&At1[off];
    }
    #pragma unroll
    for (int nt = 0; nt < 4; ++nt) {
      const int off = (wn * 64 + nt * 16 + lr) * 32 + fsw;
      b0[nt] = *(const f16x8*)&Bt0[off];
      b1[nt] = *(const f16x8*)&Bt1[off];
    }
    #pragma unroll
    for (int mt = 0; mt < 4; ++mt)
      #pragma unroll
      for (int nt = 0; nt < 4; ++nt) {
        acc[mt][nt] = __builtin_amdgcn_mfma_f32_16x16x32_f16(a0[mt], b0[nt], acc[mt][nt], 0, 0, 0);
        acc[mt][nt] = __builtin_amdgcn_mfma_f32_16x16x32_f16(a1[mt], b1[nt], acc[mt][nt], 0, 0, 0);
      }
  }

  // ---- epilogue ----
  const int region = ntile >> 1;                 // 0:Q 1:K 2:V 3:G
  const int nb = (ntile & 1) * 128;
  if (region == 3) {
    #pragma unroll
    for (int nt = 0; nt < 4; ++nt) {
      const int lcol = nb + wn * 64 + nt * 16 + lr;
      const float b = bg[lcol];
      #pragma unroll
      for (int mt = 0; mt < 4; ++mt)
        #pragma unroll
        for (int reg = 0; reg < 4; ++reg) {
          const int row = r0 + wm * 64 + mt * 16 + quad * 4 + reg;
          float v = acc[mt][nt][reg] + b;
          Gh[(size_t)row * TOTAL + lcol] = __float2half(1.0f / (1.0f + __expf(-v)));
        }
    }
  } else {
    ushort* P = (region == 0) ? Qh : (region == 1) ? Kh : Vh;
    const float scale = (region == 0) ? 0.25503534f : 1.0f;  // log2e/sqrt(32)
    #pragma unroll
    for (int nt = 0; nt < 4; ++nt) {
      const int lcol = nb + wn * 64 + nt * 16 + lr;
      const int h = lcol >> 5, d = lcol & 31;
      #pragma unroll
      for (int mt = 0; mt < 4; ++mt)
        #pragma unroll
        for (int reg = 0; reg < 4; ++reg) {
          const int row = r0 + wm * 64 + mt * 16 + quad * 4 + reg;
          const int s = row >> 8, i = row & 255;
          P[(((size_t)(i * NUM_HEADS + h)) * S_DIM + s) * HEAD_DIM + d] =
              f2h(acc[mt][nt][reg] * scale);
        }
    }
  }
}

// ---------------------------------------------------------------------------
// attn: fp16 MFMA column attention per (i,h). scores^T = K.Q^T (1 MFMA/tile),
// exp2 (scale folded into Q), P fp16 in LDS (wave-private rows, no in-loop
// barrier), out^T = Vt.P^T (1 MFMA/tile). l from ROUNDED P. No max-sub, no
// rescale. Gated O written fp16 IN PLACE over Qh (block-private slice).
// ---------------------------------------------------------------------------
__global__ __launch_bounds__(256, 3) void attn_kernel(
    const ushort* Qh, const ushort* __restrict__ Kh,
    const ushort* __restrict__ Vh, const __half* __restrict__ Gh,
    ushort* Oh) {
  __shared__ __align__(16) ushort Ph[256][72];    // 36 KB
  __shared__ __align__(16) ushort Vth[32][264];   // 16.5 KB

  const int ih = blockIdx.x;
  const int i = ih >> 3, h = ih & 7;
  const int tid = threadIdx.x;
  const int wave = tid >> 6, lane = tid & 63;
  const int lr = lane & 15, quad = lane >> 4;
  const int s_base = wave * 64;
  const size_t hbase = (size_t)ih * (S_DIM * HEAD_DIM);

  // ---- stage V^T -> LDS (fp16, once per block) ----
  {
    const uint4* vp = (const uint4*)(Vh + hbase + (size_t)tid * HEAD_DIM);
    #pragma unroll
    for (int jj = 0; jj < 4; ++jj) {
      uint4 w = vp[jj];
      unsigned ww[4] = {w.x, w.y, w.z, w.w};
      #pragma unroll
      for (int e = 0; e < 4; ++e) {
        Vth[jj * 8 + e * 2 + 0][tid] = (ushort)(ww[e] & 0xFFFFu);
        Vth[jj * 8 + e * 2 + 1][tid] = (ushort)(ww[e] >> 16);
      }
    }
  }
  __syncthreads();   // the only barrier: V is shared across waves

  f16x8 qf[4];
  #pragma unroll
  for (int ns = 0; ns < 4; ++ns)
    qf[ns] = *(const f16x8*)(Qh + hbase +
                             (size_t)(s_base + ns * 16 + lr) * HEAD_DIM + quad * 8);

  f32x4 oacc[2][4] = {};
  float lpart[4] = {};

  #pragma unroll 1
  for (int c = 0; c < 4; ++c) {
    const int t0 = c * 64;
    f16x8 kf[4];
    #pragma unroll
    for (int mt = 0; mt < 4; ++mt)
      kf[mt] = *(const f16x8*)(Kh + hbase +
                               (size_t)(t0 + mt * 16 + lr) * HEAD_DIM + quad * 8);
    // scores^T tiles: D[t][s]; lane holds 4 consecutive t at one s
    #pragma unroll
    for (int mt = 0; mt < 4; ++mt) {
      #pragma unroll
      for (int ns = 0; ns < 4; ++ns) {
        f32x4 sc = {};
        sc = __builtin_amdgcn_mfma_f32_16x16x32_f16(kf[mt], qf[ns], sc, 0, 0, 0);
        ushort u0 = f2h(exp2f(sc[0])), u1 = f2h(exp2f(sc[1]));
        ushort u2 = f2h(exp2f(sc[2])), u3 = f2h(exp2f(sc[3]));
        lpart[ns] += (h2f(u0) + h2f(u1)) + (h2f(u2) + h2f(u3));
        ushort4 pk = make_ushort4(u0, u1, u2, u3);
        *(ushort4*)&Ph[s_base + ns * 16 + lr][mt * 16 + quad * 4] = pk;
      }
    }
    // PV: out^T[d][s] += Vt(chunk) x P^T
    #pragma unroll
    for (int ks = 0; ks < 2; ++ks) {
      const int tq = t0 + ks * 32 + quad * 8;
      f16x8 v0 = *(const f16x8*)&Vth[lr][tq];
      f16x8 v1 = *(const f16x8*)&Vth[16 + lr][tq];
      #pragma unroll
      for (int ns = 0; ns < 4; ++ns) {
        f16x8 pf = *(const f16x8*)&Ph[s_base + ns * 16 + lr][ks * 32 + quad * 8];
        oacc[0][ns] = __builtin_amdgcn_mfma_f32_16x16x32_f16(v0, pf, oacc[0][ns], 0, 0, 0);
        oacc[1][ns] = __builtin_amdgcn_mfma_f32_16x16x32_f16(v1, pf, oacc[1][ns], 0, 0, 0);
      }
    }
  }

  float invl[4];
  #pragma unroll
  for (int ns = 0; ns < 4; ++ns) {
    float v = lpart[ns];
    v += __shfl_xor(v, 16);
    v += __shfl_xor(v, 32);
    invl[ns] = 1.0f / v;
  }

  // ---- epilogue: gate + normalize, fp16 in place over Qh ----
  #pragma unroll
  for (int ns = 0; ns < 4; ++ns) {
    const int s = s_base + ns * 16 + lr;
    const __half* gp = Gh + ((size_t)(s * I_DIM + i)) * TOTAL + h * HEAD_DIM;
    #pragma unroll
    for (int md = 0; md < 2; ++md) {
      const int d0 = md * 16 + quad * 4;
      ushort4 ov;
      ov.x = f2h(__half2float(gp[d0 + 0]) * oacc[md][ns][0] * invl[ns]);
      ov.y = f2h(__half2float(gp[d0 + 1]) * oacc[md][ns][1] * invl[ns]);
      ov.z = f2h(__half2float(gp[d0 + 2]) * oacc[md][ns][2] * invl[ns]);
      ov.w = f2h(__half2float(gp[d0 + 3]) * oacc[md][ns][3] * invl[ns]);
      *(ushort4*)(Oh + hbase + (size_t)s * HEAD_DIM + d0) = ov;
    }
  }
}

// ---------------------------------------------------------------------------
// out: pure fp16 GEMM. A = O fp16 (i,h,s,d); B = Wo^T fp16 [n][k].
// m-tile = (s fixed, 128 i's); BK=64 = two heads/iter. XCD-swizzled grid.
// ---------------------------------------------------------------------------
__global__ __launch_bounds__(256) void out_kernel(
    const ushort* __restrict__ Oh, const ushort* __restrict__ Woh,
    const float* __restrict__ bo, float* __restrict__ out) {
  __shared__ __align__(16) ushort At0[128 * 32];
  __shared__ __align__(16) ushort At1[128 * 32];
  __shared__ __align__(16) ushort Bt0[128 * 32];
  __shared__ __align__(16) ushort Bt1[128 * 32];

  const int bid = blockIdx.x;                    // 0..1023
  const int xcd = bid & 7;
  const int j   = bid >> 3;                      // 0..127
  const int ntile = j & 1;
  const int rg    = (xcd << 6) + (j >> 1);       // 0..511
  const int n0 = ntile * 128;
  const int s  = rg >> 1;
  const int i0 = (rg & 1) * 128;
  const int tid = threadIdx.x;
  const int wave = tid >> 6, lane = tid & 63;
  const int wm = wave >> 1, wn = wave & 1;
  const int lr = lane & 15, quad = lane >> 4;
  const int fsw = (quad ^ ((lr >> 1) & 3)) * 8;

  const int slot = wave * 64 + lane;
  const int row0 = slot >> 2;
  const int kc   = ((slot & 3) ^ ((row0 >> 1) & 3)) * 8;

  // O element: i*65536 + h*8192 + s*32 + d
  const ushort* pA = Oh + (size_t)(i0 + row0) * 65536 + (size_t)s * 32 + kc;
  const ushort* pB = Woh + (size_t)(n0 + row0) * 256 + kc;
  const int ld0 = wave * 512;
  const int ld1 = 2048 + wave * 512;

  f32x4 acc[4][4] = {};

  for (int kk = 0; kk < 4; ++kk) {
    __syncthreads();
    gl16(pA,               At0 + ld0); gl16(pA + (size_t)64 * 65536,        At0 + ld1);
    gl16(pA + 8192,        At1 + ld0); gl16(pA + (size_t)64 * 65536 + 8192, At1 + ld1);
    gl16(pB,               Bt0 + ld0); gl16(pB + 64 * 256,                  Bt0 + ld1);
    gl16(pB + 32,          Bt1 + ld0); gl16(pB + 64 * 256 + 32,             Bt1 + ld1);
    pA += 16384;                                  // next head pair
    pB += 64;
    __syncthreads();

    f16x8 a0[4], a1[4], b0[4], b1[4];
    #pragma unroll
    for (int mt = 0; mt < 4; ++mt) {
      const int off = (wm * 64 + mt * 16 + lr) * 32 + fsw;
      a0[mt] = *(const f16x8*)&At0[off];
      a1[mt] = *(const f16x8*)&At1[off];
    }
    #pragma unroll
    for (int nt = 0; nt < 4; ++nt) {
      const int off = (wn * 64 + nt * 16 + lr) * 32 + fsw;
      b0[nt] = *(const f16x8*)&Bt0[off];
      b1[nt] = *(const f16x8*)&Bt1[off];
    }
    #pragma unroll
    for (int mt = 0; mt < 4; ++mt)
      #pragma unroll
      for (int nt = 0; nt < 4; ++nt) {
        acc[mt][nt] = __builtin_amdgcn_mfma_f32_16x16x32_f16(a0[mt], b0[nt], acc[mt][nt], 0, 0, 0);
        acc[mt][nt] = __builtin_amdgcn_mfma_f32_16x16x32_f16(a1[mt], b1[nt], acc[mt][nt], 0, 0, 0);
      }
  }

  #pragma unroll
  for (int nt = 0; nt < 4; ++nt) {
    const int col = n0 + wn * 64 + nt * 16 + lr;
    const float b = bo[col];
    #pragma unroll
    for (int mt = 0; mt < 4; ++mt)
      #pragma unroll
      for (int reg = 0; reg < 4; ++reg) {
        const int mloc = wm * 64 + mt * 16 + quad * 4 + reg;
        out[((size_t)s * 256 + i0 + mloc) * C_S + col] = acc[mt][nt][reg] + b;
      }
  }
}

// ---------------------------------------------------------------------------
extern "C" void kernel_launch(void* const* d_in, const int* in_sizes, int n_in,
                              void* d_out, int out_size, void* d_ws, size_t ws_size,
                              hipStream_t stream) {
  const float* msa   = (const float*)d_in[0];
  const float* gamma = (const float*)d_in[1];
  const float* beta  = (const float*)d_in[2];
  const float* Wq    = (const float*)d_in[3];
  const float* Wk    = (const float*)d_in[4];
  const float* Wv    = (const float*)d_in[5];
  const float* Wg    = (const float*)d_in[6];
  const float* bg    = (const float*)d_in[7];
  const float* Wo    = (const float*)d_in[8];
  const float* bo    = (const float*)d_in[9];
  float* out = (float*)d_out;

  const size_t PLANE = (size_t)NROWS * TOTAL;    // 16.78M elements
  // ws: Q/K/V fp16 (100.6MB) + G fp16 (33.5) + W fp16 (0.66) = ~135 MB
  ushort* Qh = (ushort*)d_ws;                    // (i,h,s,d); O overwrites it
  ushort* Kh = Qh + PLANE;
  ushort* Vh = Kh + PLANE;
  __half* Gh = (__half*)(Vh + PLANE);            // (row,col) sigmoid
  ushort* Wch = (ushort*)((ushort*)Gh + PLANE);  // [1024][256]
  ushort* Woh = Wch + 1024 * 256;                // [256][256]
  // X fp16 lives in d_out (33.5MB of 67MB, dead before out_kernel writes)
  ushort* Xh = (ushort*)d_out;

  prep_w_kernel<<<1280, 256, 0, stream>>>(Wq, Wk, Wv, Wg, Wo, Wch, Woh);
  prep_x_kernel<<<NROWS / 4, 256, 0, stream>>>(msa, gamma, beta, Xh);
  proj_kernel<<<4096, 256, 0, stream>>>(Xh, Wch, bg, Qh, Kh, Vh, Gh);
  attn_kernel<<<I_DIM * NUM_HEADS, 256, 0, stream>>>(Qh, Kh, Vh, Gh, Qh);
  out_kernel<<<1024, 256, 0, stream>>>(Qh, Woh, bo, out);
}

// Round 7
// 284.182 us; speedup vs baseline: 4.2429x; 1.0861x over previous
//
#include <hip/hip_runtime.h>
#include <hip/hip_fp16.h>
#include <math.h>

#define C_S 256
#define NUM_HEADS 8
#define HEAD_DIM 32
#define TOTAL 256
#define S_DIM 256
#define I_DIM 256
#define NROWS (S_DIM * I_DIM)   // 65536
#define LN_EPS 1e-5f
#define QSCALE 0.25503534f      // log2(e)/sqrt(32)

typedef _Float16 f16x8 __attribute__((ext_vector_type(8)));   // 8 fp16 = 4 VGPR
typedef __attribute__((ext_vector_type(4))) float f32x4;

__device__ __forceinline__ ushort f2h(float x) {
  return __half_as_ushort(__float2half(x));      // RNE
}
__device__ __forceinline__ float h2f(ushort u) {
  return __half2float(__ushort_as_half(u));
}
// async global->LDS, 16B per lane; lds base must be wave-uniform.
__device__ __forceinline__ void gl16(const void* g, void* l) {
  __builtin_amdgcn_global_load_lds(
      (const __attribute__((address_space(1))) unsigned*)g,
      (__attribute__((address_space(3))) unsigned*)l, 16, 0, 0);
}

// ---------------------------------------------------------------------------
// prep_w: transpose + fp16-convert weights once.
// QKVG -> combined [1024][256] fp16 (row = mat*256+n, k contiguous);
// Wo -> [256][256] fp16.
// ---------------------------------------------------------------------------
__global__ __launch_bounds__(256) void prep_w_kernel(
    const float* __restrict__ Wq, const float* __restrict__ Wk,
    const float* __restrict__ Wv, const float* __restrict__ Wg,
    const float* __restrict__ Wo,
    ushort* __restrict__ Wch, ushort* __restrict__ Woh) {
  const int b = blockIdx.x;            // 0..1279
  const int mat = b >> 8, n = b & 255;
  const int k = threadIdx.x;
  const float* W = (mat == 0) ? Wq : (mat == 1) ? Wk
                  : (mat == 2) ? Wv : (mat == 3) ? Wg : Wo;
  ushort h = f2h(W[(size_t)k * 256 + n]);
  if (mat < 4) Wch[((size_t)(mat * 256 + n)) * 256 + k] = h;
  else         Woh[(size_t)n * 256 + k] = h;
}

// ---------------------------------------------------------------------------
// prep_x: LN stats + apply + fp16-convert, once. One wave per row.
// X fp16 lives in d_out (dead until out_kernel overwrites it).
// ---------------------------------------------------------------------------
__global__ __launch_bounds__(256) void prep_x_kernel(
    const float* __restrict__ msa, const float* __restrict__ gamma,
    const float* __restrict__ beta, ushort* __restrict__ Xh) {
  const int row  = blockIdx.x * 4 + (threadIdx.x >> 6);
  const int lane = threadIdx.x & 63;
  float4 v = ((const float4*)(msa + (size_t)row * C_S))[lane];
  float sum = v.x + v.y + v.z + v.w;
  float sq  = v.x*v.x + v.y*v.y + v.z*v.z + v.w*v.w;
  #pragma unroll
  for (int off = 1; off < 64; off <<= 1) {
    sum += __shfl_xor(sum, off);
    sq  += __shfl_xor(sq, off);
  }
  float mu = sum * (1.0f / 256.0f);
  float rs = rsqrtf(sq * (1.0f / 256.0f) - mu * mu + LN_EPS);
  float4 gv = ((const float4*)gamma)[lane];
  float4 bv = ((const float4*)beta)[lane];
  ushort4 hh;
  hh.x = f2h((v.x - mu) * rs * gv.x + bv.x);
  hh.y = f2h((v.y - mu) * rs * gv.y + bv.y);
  hh.z = f2h((v.z - mu) * rs * gv.z + bv.z);
  hh.w = f2h((v.w - mu) * rs * gv.w + bv.w);
  *(ushort4*)(Xh + (size_t)row * 256 + lane * 4) = hh;
}

// ---------------------------------------------------------------------------
// fused_attn: one block per (i,h). Each wave owns 64 s/t rows.
//  Phase A: K^T, V^T GEMMs (A = W^T frags from Wch, B = X frags from global;
//           both identical addressing to the validated attn fragment loads).
//           K -> Kls[t][d] (packed b64), V -> Vth[d][t] (validated layout).
//  Phase B: Q^T (scaled, via wave-private LDS corner -> B-operand regs),
//           G^T (stays in f32 regs; its D-layout col=s,row=d matches oacc).
//  One __syncthreads. Then the R6-validated attention chunk loop, with K
//  fragments from LDS. Epilogue gates from registers, writes O fp16 (i,h,s,d).
// ---------------------------------------------------------------------------
__global__ __launch_bounds__(256, 2) void fused_attn_kernel(
    const ushort* __restrict__ Xh,    // [65536][256], row = s*256+i
    const ushort* __restrict__ Wch,   // [1024][256], row = mat*256+n
    const float* __restrict__ bg,
    ushort* __restrict__ Oh) {        // (i,h,s,d) fp16
  __shared__ __align__(16) ushort Kls[256][40];   // 20.5 KB  K[t][d]
  __shared__ __align__(16) ushort Vth[32][264];   // 16.9 KB  V^T[d][t]
  __shared__ __align__(16) ushort PQ[256][72];    // 36.9 KB  Q (cols 0..31) then P

  const int bid = blockIdx.x;
  const int xcd = bid & 7, j = bid >> 3;
  const int h = j & 7;
  const int i = (xcd << 5) + (j >> 3);            // 32 consecutive i per XCD
  const int ih = i * NUM_HEADS + h;
  const int tid = threadIdx.x;
  const int wave = tid >> 6, lane = tid & 63;
  const int lr = lane & 15, quad = lane >> 4;
  const int s_base = wave * 64;
  const size_t hbase = (size_t)ih * (S_DIM * HEAD_DIM);

  // X B-frag base: row (s,i) = (s*256+i), element quad*8 within k-chunk
  const ushort* xr0 = Xh + ((size_t)(s_base + lr) * 256 + i) * 256 + quad * 8;
  // W^T A-frag base: row = mat*256 + h*32 + (mt*16+lr)
  const ushort* wr0 = Wch + ((size_t)(h * 32 + lr)) * 256 + quad * 8;

  // ---- Phase A: K^T (mat 1), V^T (mat 2) ----
  f32x4 kacc[2][4] = {}, vacc[2][4] = {};
  #pragma unroll
  for (int kb = 0; kb < 8; ++kb) {
    f16x8 xb[4];
    #pragma unroll
    for (int nt = 0; nt < 4; ++nt)
      xb[nt] = *(const f16x8*)(xr0 + (size_t)nt * 16 * 65536 + kb * 32);
    f16x8 wk[2], wv[2];
    #pragma unroll
    for (int mt = 0; mt < 2; ++mt) {
      wk[mt] = *(const f16x8*)(wr0 + (size_t)1 * 65536 + mt * 4096 + kb * 32);
      wv[mt] = *(const f16x8*)(wr0 + (size_t)2 * 65536 + mt * 4096 + kb * 32);
    }
    #pragma unroll
    for (int mt = 0; mt < 2; ++mt)
      #pragma unroll
      for (int nt = 0; nt < 4; ++nt) {
        kacc[mt][nt] = __builtin_amdgcn_mfma_f32_16x16x32_f16(wk[mt], xb[nt], kacc[mt][nt], 0, 0, 0);
        vacc[mt][nt] = __builtin_amdgcn_mfma_f32_16x16x32_f16(wv[mt], xb[nt], vacc[mt][nt], 0, 0, 0);
      }
  }
  // store: D col = t (nt*16+lr within wave), row = d (mt*16+quad*4+reg)
  #pragma unroll
  for (int mt = 0; mt < 2; ++mt)
    #pragma unroll
    for (int nt = 0; nt < 4; ++nt) {
      const int t = s_base + nt * 16 + lr;
      ushort4 kp;
      kp.x = f2h(kacc[mt][nt][0]); kp.y = f2h(kacc[mt][nt][1]);
      kp.z = f2h(kacc[mt][nt][2]); kp.w = f2h(kacc[mt][nt][3]);
      *(ushort4*)&Kls[t][mt * 16 + quad * 4] = kp;           // b64 write
      #pragma unroll
      for (int reg = 0; reg < 4; ++reg)
        Vth[mt * 16 + quad * 4 + reg][t] = f2h(vacc[mt][nt][reg]);
    }

  // ---- Phase B: Q^T (mat 0), G^T (mat 3) ----
  f32x4 qacc[2][4] = {}, gacc[2][4] = {};
  #pragma unroll
  for (int kb = 0; kb < 8; ++kb) {
    f16x8 xb[4];
    #pragma unroll
    for (int nt = 0; nt < 4; ++nt)
      xb[nt] = *(const f16x8*)(xr0 + (size_t)nt * 16 * 65536 + kb * 32);
    f16x8 wq[2], wg[2];
    #pragma unroll
    for (int mt = 0; mt < 2; ++mt) {
      wq[mt] = *(const f16x8*)(wr0 + (size_t)0 * 65536 + mt * 4096 + kb * 32);
      wg[mt] = *(const f16x8*)(wr0 + (size_t)3 * 65536 + mt * 4096 + kb * 32);
    }
    #pragma unroll
    for (int mt = 0; mt < 2; ++mt)
      #pragma unroll
      for (int nt = 0; nt < 4; ++nt) {
        qacc[mt][nt] = __builtin_amdgcn_mfma_f32_16x16x32_f16(wq[mt], xb[nt], qacc[mt][nt], 0, 0, 0);
        gacc[mt][nt] = __builtin_amdgcn_mfma_f32_16x16x32_f16(wg[mt], xb[nt], gacc[mt][nt], 0, 0, 0);
      }
  }
  // Q -> wave-private LDS rows (cols 0..31 of PQ), then frag regs
  #pragma unroll
  for (int mt = 0; mt < 2; ++mt)
    #pragma unroll
    for (int nt = 0; nt < 4; ++nt) {
      const int s = s_base + nt * 16 + lr;
      ushort4 qp;
      qp.x = f2h(qacc[mt][nt][0] * QSCALE); qp.y = f2h(qacc[mt][nt][1] * QSCALE);
      qp.z = f2h(qacc[mt][nt][2] * QSCALE); qp.w = f2h(qacc[mt][nt][3] * QSCALE);
      *(ushort4*)&PQ[s][mt * 16 + quad * 4] = qp;
    }
  f16x8 qf[4];
  #pragma unroll
  for (int ns = 0; ns < 4; ++ns)
    qf[ns] = *(const f16x8*)&PQ[s_base + ns * 16 + lr][quad * 8];
  // G: sigmoid in registers; layout (col=s, row=d) == oacc layout
  f32x4 gv[2][4];
  #pragma unroll
  for (int mt = 0; mt < 2; ++mt) {
    float4 bgv = *(const float4*)(bg + h * 32 + mt * 16 + quad * 4);
    float bga[4] = {bgv.x, bgv.y, bgv.z, bgv.w};
    #pragma unroll
    for (int nt = 0; nt < 4; ++nt)
      #pragma unroll
      for (int reg = 0; reg < 4; ++reg)
        gv[mt][nt][reg] = 1.0f / (1.0f + __expf(-(gacc[mt][nt][reg] + bga[reg])));
  }

  __syncthreads();   // K/V (and Q corner) visible; the only barrier

  // ---- attention chunk loop (R6-validated), K frags now from LDS ----
  f32x4 oacc[2][4] = {};
  float lpart[4] = {};
  #pragma unroll 1
  for (int c = 0; c < 4; ++c) {
    const int t0 = c * 64;
    f16x8 kf[4];
    #pragma unroll
    for (int mt = 0; mt < 4; ++mt)
      kf[mt] = *(const f16x8*)&Kls[t0 + mt * 16 + lr][quad * 8];
    #pragma unroll
    for (int mt = 0; mt < 4; ++mt) {
      #pragma unroll
      for (int ns = 0; ns < 4; ++ns) {
        f32x4 sc = {};
        sc = __builtin_amdgcn_mfma_f32_16x16x32_f16(kf[mt], qf[ns], sc, 0, 0, 0);
        ushort u0 = f2h(exp2f(sc[0])), u1 = f2h(exp2f(sc[1]));
        ushort u2 = f2h(exp2f(sc[2])), u3 = f2h(exp2f(sc[3]));
        lpart[ns] += (h2f(u0) + h2f(u1)) + (h2f(u2) + h2f(u3));
        ushort4 pk = make_ushort4(u0, u1, u2, u3);
        *(ushort4*)&PQ[s_base + ns * 16 + lr][mt * 16 + quad * 4] = pk;
      }
    }
    #pragma unroll
    for (int ks = 0; ks < 2; ++ks) {
      const int tq = t0 + ks * 32 + quad * 8;
      f16x8 v0 = *(const f16x8*)&Vth[lr][tq];
      f16x8 v1 = *(const f16x8*)&Vth[16 + lr][tq];
      #pragma unroll
      for (int ns = 0; ns < 4; ++ns) {
        f16x8 pf = *(const f16x8*)&PQ[s_base + ns * 16 + lr][ks * 32 + quad * 8];
        oacc[0][ns] = __builtin_amdgcn_mfma_f32_16x16x32_f16(v0, pf, oacc[0][ns], 0, 0, 0);
        oacc[1][ns] = __builtin_amdgcn_mfma_f32_16x16x32_f16(v1, pf, oacc[1][ns], 0, 0, 0);
      }
    }
  }

  float invl[4];
  #pragma unroll
  for (int ns = 0; ns < 4; ++ns) {
    float v = lpart[ns];
    v += __shfl_xor(v, 16);
    v += __shfl_xor(v, 32);
    invl[ns] = 1.0f / v;
  }

  // ---- epilogue: gate from registers, write O fp16 (i,h,s,d) ----
  #pragma unroll
  for (int ns = 0; ns < 4; ++ns) {
    const int s = s_base + ns * 16 + lr;
    #pragma unroll
    for (int md = 0; md < 2; ++md) {
      const int d0 = md * 16 + quad * 4;
      ushort4 ov;
      ov.x = f2h(gv[md][ns][0] * oacc[md][ns][0] * invl[ns]);
      ov.y = f2h(gv[md][ns][1] * oacc[md][ns][1] * invl[ns]);
      ov.z = f2h(gv[md][ns][2] * oacc[md][ns][2] * invl[ns]);
      ov.w = f2h(gv[md][ns][3] * oacc[md][ns][3] * invl[ns]);
      *(ushort4*)(Oh + hbase + (size_t)s * HEAD_DIM + d0) = ov;
    }
  }
}

// ---------------------------------------------------------------------------
// out: pure fp16 GEMM (unchanged from R6). A = O fp16 (i,h,s,d);
// B = Wo^T fp16 [n][k]. m-tile = (s fixed, 128 i's); BK=64 = two heads/iter.
// ---------------------------------------------------------------------------
__global__ __launch_bounds__(256) void out_kernel(
    const ushort* __restrict__ Oh, const ushort* __restrict__ Woh,
    const float* __restrict__ bo, float* __restrict__ out) {
  __shared__ __align__(16) ushort At0[128 * 32];
  __shared__ __align__(16) ushort At1[128 * 32];
  __shared__ __align__(16) ushort Bt0[128 * 32];
  __shared__ __align__(16) ushort Bt1[128 * 32];

  const int bid = blockIdx.x;                    // 0..1023
  const int xcd = bid & 7;
  const int j   = bid >> 3;                      // 0..127
  const int ntile = j & 1;
  const int rg    = (xcd << 6) + (j >> 1);       // 0..511
  const int n0 = ntile * 128;
  const int s  = rg >> 1;
  const int i0 = (rg & 1) * 128;
  const int tid = threadIdx.x;
  const int wave = tid >> 6, lane = tid & 63;
  const int wm = wave >> 1, wn = wave & 1;
  const int lr = lane & 15, quad = lane >> 4;
  const int fsw = (quad ^ ((lr >> 1) & 3)) * 8;

  const int slot = wave * 64 + lane;
  const int row0 = slot >> 2;
  const int kc   = ((slot & 3) ^ ((row0 >> 1) & 3)) * 8;

  const ushort* pA = Oh + (size_t)(i0 + row0) * 65536 + (size_t)s * 32 + kc;
  const ushort* pB = Woh + (size_t)(n0 + row0) * 256 + kc;
  const int ld0 = wave * 512;
  const int ld1 = 2048 + wave * 512;

  f32x4 acc[4][4] = {};

  for (int kk = 0; kk < 4; ++kk) {
    __syncthreads();
    gl16(pA,               At0 + ld0); gl16(pA + (size_t)64 * 65536,        At0 + ld1);
    gl16(pA + 8192,        At1 + ld0); gl16(pA + (size_t)64 * 65536 + 8192, At1 + ld1);
    gl16(pB,               Bt0 + ld0); gl16(pB + 64 * 256,                  Bt0 + ld1);
    gl16(pB + 32,          Bt1 + ld0); gl16(pB + 64 * 256 + 32,             Bt1 + ld1);
    pA += 16384;                                  // next head pair
    pB += 64;
    __syncthreads();

    f16x8 a0[4], a1[4], b0[4], b1[4];
    #pragma unroll
    for (int mt = 0; mt < 4; ++mt) {
      const int off = (wm * 64 + mt * 16 + lr) * 32 + fsw;
      a0[mt] = *(const f16x8*)&At0[off];
      a1[mt] = *(const f16x8*)&At1[off];
    }
    #pragma unroll
    for (int nt = 0; nt < 4; ++nt) {
      const int off = (wn * 64 + nt * 16 + lr) * 32 + fsw;
      b0[nt] = *(const f16x8*)&Bt0[off];
      b1[nt] = *(const f16x8*)&Bt1[off];
    }
    #pragma unroll
    for (int mt = 0; mt < 4; ++mt)
      #pragma unroll
      for (int nt = 0; nt < 4; ++nt) {
        acc[mt][nt] = __builtin_amdgcn_mfma_f32_16x16x32_f16(a0[mt], b0[nt], acc[mt][nt], 0, 0, 0);
        acc[mt][nt] = __builtin_amdgcn_mfma_f32_16x16x32_f16(a1[mt], b1[nt], acc[mt][nt], 0, 0, 0);
      }
  }

  #pragma unroll
  for (int nt = 0; nt < 4; ++nt) {
    const int col = n0 + wn * 64 + nt * 16 + lr;
    const float b = bo[col];
    #pragma unroll
    for (int mt = 0; mt < 4; ++mt)
      #pragma unroll
      for (int reg = 0; reg < 4; ++reg) {
        const int mloc = wm * 64 + mt * 16 + quad * 4 + reg;
        out[((size_t)s * 256 + i0 + mloc) * C_S + col] = acc[mt][nt][reg] + b;
      }
  }
}

// ---------------------------------------------------------------------------
extern "C" void kernel_launch(void* const* d_in, const int* in_sizes, int n_in,
                              void* d_out, int out_size, void* d_ws, size_t ws_size,
                              hipStream_t stream) {
  const float* msa   = (const float*)d_in[0];
  const float* gamma = (const float*)d_in[1];
  const float* beta  = (const float*)d_in[2];
  const float* Wq    = (const float*)d_in[3];
  const float* Wk    = (const float*)d_in[4];
  const float* Wv    = (const float*)d_in[5];
  const float* Wg    = (const float*)d_in[6];
  const float* bg    = (const float*)d_in[7];
  const float* Wo    = (const float*)d_in[8];
  const float* bo    = (const float*)d_in[9];
  float* out = (float*)d_out;

  const size_t PLANE = (size_t)NROWS * TOTAL;    // 16.78M elements
  // ws: O fp16 (33.5 MB) + W fp16 (0.66 MB)
  ushort* Oh  = (ushort*)d_ws;                   // (i,h,s,d)
  ushort* Wch = Oh + PLANE;                      // [1024][256]
  ushort* Woh = Wch + 1024 * 256;                // [256][256]
  // X fp16 lives in d_out (33.5 MB of 67 MB, dead before out_kernel writes)
  ushort* Xh = (ushort*)d_out;

  prep_w_kernel<<<1280, 256, 0, stream>>>(Wq, Wk, Wv, Wg, Wo, Wch, Woh);
  prep_x_kernel<<<NROWS / 4, 256, 0, stream>>>(msa, gamma, beta, Xh);
  fused_attn_kernel<<<I_DIM * NUM_HEADS, 256, 0, stream>>>(Xh, Wch, bg, Oh);
  out_kernel<<<1024, 256, 0, stream>>>(Oh, Woh, bo, out);
}